// Round 3
// baseline (1099.304 us; speedup 1.0000x reference)
//
#include <hip/hip_runtime.h>
#include <stdint.h>

// Problem constants (reference: N=2048, A=100)
#define NN 2048
#define AA 100
#define NT 32   // 64-wide tiles per side (2048/64)

// ---------------------------------------------------------------------------
// Alignment-templated global float4 access (fallback path may be 4B-aligned).
// ---------------------------------------------------------------------------
template<bool AL> __device__ __forceinline__ float4 ld4(const float* __restrict__ p) {
  if (AL) return *(const float4*)p;
  return make_float4(p[0], p[1], p[2], p[3]);
}
template<bool AL> __device__ __forceinline__ void st4(float* __restrict__ p, float4 v) {
  if (AL) { *(float4*)p = v; }
  else { p[0] = v.x; p[1] = v.y; p[2] = v.z; p[3] = v.w; }
}

// ---------------------------------------------------------------------------
// k=64 min-plus inner loop: c[4][4] = min(c, A(i0-rows) (x) B(j0-cols)).
// All LDS reads are b128; fminf chains fold to v_min3_f32 pairs.
// ---------------------------------------------------------------------------
__device__ __forceinline__ void minplus16(const float (*A)[68], const float (*B)[68],
                                          float c[4][4], int i0, int j0) {
#pragma unroll 4
  for (int k4 = 0; k4 < 16; ++k4) {
    const int k = k4 * 4;
    float4 a0 = *(const float4*)&A[i0 + 0][k];
    float4 a1 = *(const float4*)&A[i0 + 1][k];
    float4 a2 = *(const float4*)&A[i0 + 2][k];
    float4 a3 = *(const float4*)&A[i0 + 3][k];
    float4 b0 = *(const float4*)&B[k + 0][j0];
    float4 b1 = *(const float4*)&B[k + 1][j0];
    float4 b2 = *(const float4*)&B[k + 2][j0];
    float4 b3 = *(const float4*)&B[k + 3][j0];
#define MP1(ii, jj, f)                                                           \
    c[ii][jj] = fminf(fminf(fminf(fminf(c[ii][jj], a##ii.x + b0.f),              \
                                  a##ii.y + b1.f),                               \
                            a##ii.z + b2.f),                                     \
                      a##ii.w + b3.f)
#define MP_ROW(ii) MP1(ii, 0, x); MP1(ii, 1, y); MP1(ii, 2, z); MP1(ii, 3, w)
    MP_ROW(0); MP_ROW(1); MP_ROW(2); MP_ROW(3);
#undef MP_ROW
#undef MP1
  }
}

// ---------------------------------------------------------------------------
// Sequential-k Floyd-Warshall closure of the 64x64 tile in S.
// Thread owns c[4][4] == S's (i0,j0) block; S current on entry (caller
// barriers). Row k / col k are fixed points of step k, so only row/col k+1
// owners write back per step; one barrier per k. kq unrolled => static c[].
// ---------------------------------------------------------------------------
__device__ __forceinline__ void close_seq(float (*S)[68], float c[4][4],
                                          int i0, int j0, int ty, int tx) {
  for (int kb = 0; kb < 16; ++kb) {
#pragma unroll
    for (int kq = 0; kq < 4; ++kq) {
      const int k = kb * 4 + kq;
      float4 br = *(const float4*)&S[k][j0];
      float a0 = S[i0 + 0][k];
      float a1 = S[i0 + 1][k];
      float a2 = S[i0 + 2][k];
      float a3 = S[i0 + 3][k];
      c[0][0] = fminf(c[0][0], a0 + br.x); c[0][1] = fminf(c[0][1], a0 + br.y);
      c[0][2] = fminf(c[0][2], a0 + br.z); c[0][3] = fminf(c[0][3], a0 + br.w);
      c[1][0] = fminf(c[1][0], a1 + br.x); c[1][1] = fminf(c[1][1], a1 + br.y);
      c[1][2] = fminf(c[1][2], a1 + br.z); c[1][3] = fminf(c[1][3], a1 + br.w);
      c[2][0] = fminf(c[2][0], a2 + br.x); c[2][1] = fminf(c[2][1], a2 + br.y);
      c[2][2] = fminf(c[2][2], a2 + br.z); c[2][3] = fminf(c[2][3], a2 + br.w);
      c[3][0] = fminf(c[3][0], a3 + br.x); c[3][1] = fminf(c[3][1], a3 + br.y);
      c[3][2] = fminf(c[3][2], a3 + br.z); c[3][3] = fminf(c[3][3], a3 + br.w);
      const int kn = k + 1;
      const int ii = (kq + 1) & 3;   // == kn - i0 (resp. kn - j0) when owner
      if (kn < 64) {
        if ((kn >> 2) == ty)
          *(float4*)&S[kn][j0] = make_float4(c[ii][0], c[ii][1], c[ii][2], c[ii][3]);
        if ((kn >> 2) == tx) {
          S[i0 + 0][kn] = c[0][ii];
          S[i0 + 1][kn] = c[1][ii];
          S[i0 + 2][kn] = c[2][ii];
          S[i0 + 3][kn] = c[3][ii];
        }
      }
      __syncthreads();
    }
  }
}

// ---------------------------------------------------------------------------
// Custom two-level grid barrier. Requires all blocks co-resident (guaranteed
// by cooperative launch). Layout in int units within Wi (= workspace base):
//   Wi[128]          root counter   (own 128B line)
//   Wi[160]          generation     (own 128B line)
//   Wi[192 + 32*bx]  leaf counters  (one 128B line per bx, 32 arrivals each)
// All zeroed by a stream-ordered memset before the kernel. Sense-reversing
// via generation compare-to-entry-value (absolute value irrelevant).
// Release: every thread __threadfence()s before arrival (writes reach the
// coherence point); acquire: every thread __threadfence()s after release
// (stale per-XCD L2 lines invalidated).
// ---------------------------------------------------------------------------
#define GB_ROOT 128
#define GB_GEN  160
#define GB_LEAF 192

__device__ __forceinline__ void gridbar(int* Wi, int leafid) {
  __syncthreads();
  __threadfence();     // release this thread's prior global writes
  if (threadIdx.x == 0) {
    int* root = Wi + GB_ROOT;
    int* gen  = Wi + GB_GEN;
    int* leaf = Wi + GB_LEAF + leafid * 32;
    int g = __hip_atomic_load(gen, __ATOMIC_RELAXED, __HIP_MEMORY_SCOPE_AGENT);
    int la = __hip_atomic_fetch_add(leaf, 1, __ATOMIC_ACQ_REL, __HIP_MEMORY_SCOPE_AGENT);
    bool wait = true;
    if (la == 31) {                      // last arriver in this leaf
      __hip_atomic_store(leaf, 0, __ATOMIC_RELAXED, __HIP_MEMORY_SCOPE_AGENT);
      int ra = __hip_atomic_fetch_add(root, 1, __ATOMIC_ACQ_REL, __HIP_MEMORY_SCOPE_AGENT);
      if (ra == 31) {                    // last leaf -> release everyone
        __hip_atomic_store(root, 0, __ATOMIC_RELAXED, __HIP_MEMORY_SCOPE_AGENT);
        __hip_atomic_fetch_add(gen, 1, __ATOMIC_RELEASE, __HIP_MEMORY_SCOPE_AGENT);
        wait = false;
      }
    }
    if (wait) {
      int it = 0;
      while (__hip_atomic_load(gen, __ATOMIC_ACQUIRE, __HIP_MEMORY_SCOPE_AGENT) == g) {
        if (++it > 32) __builtin_amdgcn_s_sleep(2);
      }
    }
  }
  __syncthreads();
  __threadfence();     // acquire: invalidate stale cached lines before reads
}

// ===========================================================================
// COOPERATIVE PERSISTENT FW KERNEL
// Block (by,bx) owns tile (by,bx) in registers for all 32 rounds. Global dist
// is used ONLY for cross-tile communication (row r / col r + closed diag) and
// the final publish. 2 custom grid barriers per round (the ~11us/sync
// cg::grid.sync was the r2 bottleneck: VALUBusy 3%).
// ===========================================================================
__global__ __launch_bounds__(256, 4) void fw_persist(
    const float* __restrict__ mg, const float* __restrict__ nw,
    float* __restrict__ dist, int* __restrict__ Wi) {
  __shared__ __align__(16) float As[64][68];
  __shared__ __align__(16) float Bs[64][68];
  const int bx = blockIdx.x, by = blockIdx.y;
  const int t = threadIdx.x;
  const int tx = t & 15, ty = t >> 4;
  const int i0 = ty * 4, j0 = tx * 4;

  // ---- init: build w tile (by,bx) directly into registers (fused build_w) --
  // Bs[c][r] = mg[bx*64+r][by*64+c]  (transposed stage of mg tile (bx,by))
#pragma unroll
  for (int l = 0; l < 4; ++l) {
    int idx = l * 256 + t;
    int r = idx >> 4, c4 = (idx & 15) * 4;
    float4 g = *(const float4*)&mg[(bx * 64 + r) * NN + by * 64 + c4];
    Bs[c4 + 0][r] = g.x; Bs[c4 + 1][r] = g.y;
    Bs[c4 + 2][r] = g.z; Bs[c4 + 3][r] = g.w;
  }
  __syncthreads();
  float c[4][4];
  {
    float4 nwj = *(const float4*)&nw[bx * 64 + j0];
#pragma unroll
    for (int ii = 0; ii < 4; ++ii) {
      int rl = i0 + ii;
      int i = by * 64 + rl;
      float nwi = nw[i];
      float4 m = *(const float4*)&mg[i * NN + bx * 64 + j0];
      float4 bt = *(const float4*)&Bs[rl][j0];   // = mg[j][i]
      float av[4] = {m.x * nwi, m.y * nwi, m.z * nwi, m.w * nwi};
      float bv[4] = {bt.x * nwj.x, bt.y * nwj.y, bt.z * nwj.z, bt.w * nwj.w};
#pragma unroll
      for (int q = 0; q < 4; ++q) {
        float wa = av[q] > 0.0f ? av[q] : __builtin_huge_valf();
        float wb = bv[q] > 0.0f ? bv[q] : __builtin_huge_valf();
        float v = fminf(wa, wb);
        if (i == bx * 64 + j0 + q) v = 0.0f;
        c[ii][q] = v;
      }
    }
  }
  // block (0,0): close its tile and publish for round 0's phase A
  if (bx == 0 && by == 0) {
#pragma unroll
    for (int ii = 0; ii < 4; ++ii)
      *(float4*)&As[i0 + ii][j0] = make_float4(c[ii][0], c[ii][1], c[ii][2], c[ii][3]);
    __syncthreads();
    close_seq(As, c, i0, j0, ty, tx);
#pragma unroll
    for (int ii = 0; ii < 4; ++ii)
      *(float4*)&dist[(i0 + ii) * NN + j0] =
          make_float4(c[ii][0], c[ii][1], c[ii][2], c[ii][3]);
  }
  gridbar(Wi, bx);

  for (int r = 0; r < NT; ++r) {
    // ---- phase A: cross tiles update against closed diag, then publish ----
    const bool isDiag = (by == r) && (bx == r);
    const bool isRow  = (by == r) && !isDiag;   // tile (r,bx): C=min(C, diag(x)C)
    const bool isCol  = (bx == r) && !isDiag;   // tile (by,r): C=min(C, C(x)diag)
    if (isRow || isCol) {
      float (*Da)[68] = isRow ? As : Bs;        // diag is the A-op for row tiles
      float (*Ow)[68] = isRow ? Bs : As;
      const float* db = &dist[(r * 64) * NN + r * 64];
#pragma unroll
      for (int l = 0; l < 4; ++l) {
        int idx = l * 256 + t;
        int row = idx >> 4, c4 = (idx & 15) * 4;
        *(float4*)&Da[row][c4] = *(const float4*)&db[row * NN + c4];
      }
#pragma unroll
      for (int ii = 0; ii < 4; ++ii)
        *(float4*)&Ow[i0 + ii][j0] = make_float4(c[ii][0], c[ii][1], c[ii][2], c[ii][3]);
      __syncthreads();
      minplus16(As, Bs, c, i0, j0);
      float* ob = &dist[(by * 64) * NN + bx * 64];
#pragma unroll
      for (int ii = 0; ii < 4; ++ii)
        *(float4*)&ob[(i0 + ii) * NN + j0] =
            make_float4(c[ii][0], c[ii][1], c[ii][2], c[ii][3]);
    }
    gridbar(Wi, bx);
    // ---- phase B: off-cross tiles; (r+1,r+1) also closes for next round ----
    if (by != r && bx != r) {
      const bool closer = (bx == r + 1) && (by == r + 1) && (r + 1 < NT);
      if (closer) __builtin_amdgcn_s_setprio(1);   // critical-path tail block
      const float* ab = &dist[(by * 64) * NN + r * 64];
      const float* bb = &dist[(r * 64) * NN + bx * 64];
#pragma unroll
      for (int l = 0; l < 4; ++l) {
        int idx = l * 256 + t;
        int row = idx >> 4, c4 = (idx & 15) * 4;
        *(float4*)&As[row][c4] = *(const float4*)&ab[row * NN + c4];
        *(float4*)&Bs[row][c4] = *(const float4*)&bb[row * NN + c4];
      }
      __syncthreads();
      minplus16(As, Bs, c, i0, j0);
      if (closer) {
        __syncthreads();   // all As/Bs reads of the minplus done
#pragma unroll
        for (int ii = 0; ii < 4; ++ii)
          *(float4*)&As[i0 + ii][j0] = make_float4(c[ii][0], c[ii][1], c[ii][2], c[ii][3]);
        __syncthreads();
        close_seq(As, c, i0, j0, ty, tx);
        float* ob = &dist[((r + 1) * 64) * NN + (r + 1) * 64];
#pragma unroll
        for (int ii = 0; ii < 4; ++ii)
          *(float4*)&ob[(i0 + ii) * NN + j0] =
              make_float4(c[ii][0], c[ii][1], c[ii][2], c[ii][3]);
        __builtin_amdgcn_s_setprio(0);
      }
    }
    gridbar(Wi, bx);
  }

  // ---- final publish of all tiles for cv_kernel ----
  float* ob = &dist[(by * 64) * NN + bx * 64];
#pragma unroll
  for (int ii = 0; ii < 4; ++ii)
    *(float4*)&ob[(i0 + ii) * NN + j0] =
        make_float4(c[ii][0], c[ii][1], c[ii][2], c[ii][3]);
}

// ===========================================================================
// FALLBACK multi-dispatch path (r1 kernels, unchanged)
// ===========================================================================
template<bool AL>
__global__ __launch_bounds__(256) void build_w_kernel(
    const float* __restrict__ mg, const float* __restrict__ nw,
    float* __restrict__ w) {
  __shared__ float Tt[64][65];
  __shared__ __align__(16) float As[64][68];
  int bi = blockIdx.y, bj = blockIdx.x;
  int t = threadIdx.x;
  const bool diag0 = (bi == 0) && (bj == 0);
#pragma unroll
  for (int l = 0; l < 4; ++l) {
    int idx = l * 256 + t;
    int r = idx >> 4, c4 = (idx & 15) * 4;
    float4 g = *(const float4*)&mg[(bj * 64 + r) * NN + bi * 64 + c4];
    Tt[c4 + 0][r] = g.x; Tt[c4 + 1][r] = g.y;
    Tt[c4 + 2][r] = g.z; Tt[c4 + 3][r] = g.w;
  }
  __syncthreads();
#pragma unroll
  for (int l = 0; l < 4; ++l) {
    int idx = l * 256 + t;
    int r = idx >> 4, c4 = (idx & 15) * 4;
    int i = bi * 64 + r, j = bj * 64 + c4;
    float4 m = *(const float4*)&mg[i * NN + j];
    float4 nwj = *(const float4*)&nw[j];
    float nwi = nw[i];
    float av[4] = {m.x * nwi, m.y * nwi, m.z * nwi, m.w * nwi};
    float bv[4] = {Tt[r][c4 + 0] * nwj.x, Tt[r][c4 + 1] * nwj.y,
                   Tt[r][c4 + 2] * nwj.z, Tt[r][c4 + 3] * nwj.w};
    float vv[4];
#pragma unroll
    for (int q = 0; q < 4; ++q) {
      float wa = av[q] > 0.0f ? av[q] : __builtin_huge_valf();
      float wb = bv[q] > 0.0f ? bv[q] : __builtin_huge_valf();
      float v = fminf(wa, wb);
      if (i == j + q) v = 0.0f;
      vv[q] = v;
    }
    float4 v4 = make_float4(vv[0], vv[1], vv[2], vv[3]);
    if (diag0) {
      *(float4*)&As[r][c4] = v4;
    } else {
      st4<AL>(&w[i * NN + j], v4);
    }
  }
  if (diag0) {
    __syncthreads();
    int tx = t & 15, ty = t >> 4;
    int i0 = ty * 4, j0 = tx * 4;
    float c[4][4];
#pragma unroll
    for (int ii = 0; ii < 4; ++ii) {
      float4 q = *(const float4*)&As[i0 + ii][j0];
      c[ii][0] = q.x; c[ii][1] = q.y; c[ii][2] = q.z; c[ii][3] = q.w;
    }
    close_seq(As, c, i0, j0, ty, tx);
#pragma unroll
    for (int ii = 0; ii < 4; ++ii)
      st4<AL>(&w[(i0 + ii) * NN + j0],
              make_float4(c[ii][0], c[ii][1], c[ii][2], c[ii][3]));
  }
}

template<bool AL>
__global__ __launch_bounds__(256) void fw_p2(float* __restrict__ d, int r) {
  __shared__ __align__(16) float As[64][68];
  __shared__ __align__(16) float Bs[64][68];
  int tile = blockIdx.x, side = blockIdx.y;
  if (tile == r) return;
  int t = threadIdx.x;
  int dbase = (r * 64) * NN + r * 64;
  int obase = (side == 0) ? (r * 64) * NN + tile * 64
                          : (tile * 64) * NN + r * 64;
  float (*Da)[68] = (side == 0) ? As : Bs;
  float (*Ow)[68] = (side == 0) ? Bs : As;
#pragma unroll
  for (int l = 0; l < 4; ++l) {
    int idx = l * 256 + t;
    int row = idx >> 4, c4 = (idx & 15) * 4;
    *(float4*)&Da[row][c4] = ld4<AL>(&d[dbase + row * NN + c4]);
    *(float4*)&Ow[row][c4] = ld4<AL>(&d[obase + row * NN + c4]);
  }
  int tx = t & 15, ty = t >> 4;
  int i0 = ty * 4, j0 = tx * 4;
  __syncthreads();
  float c[4][4];
#pragma unroll
  for (int ii = 0; ii < 4; ++ii) {
    float4 q = *(const float4*)&Ow[i0 + ii][j0];
    c[ii][0] = q.x; c[ii][1] = q.y; c[ii][2] = q.z; c[ii][3] = q.w;
  }
  minplus16(As, Bs, c, i0, j0);
#pragma unroll
  for (int ii = 0; ii < 4; ++ii)
    st4<AL>(&d[obase + (i0 + ii) * NN + j0],
            make_float4(c[ii][0], c[ii][1], c[ii][2], c[ii][3]));
}

template<bool AL>
__global__ __launch_bounds__(256) void fw_p3(float* __restrict__ d, int r) {
  __shared__ __align__(16) float As[64][68];
  __shared__ __align__(16) float Bs[64][68];
  int bx = blockIdx.x, by = blockIdx.y;
  if (bx == r || by == r) return;
  int t = threadIdx.x;
#pragma unroll
  for (int l = 0; l < 4; ++l) {
    int idx = l * 256 + t;
    int row = idx >> 4, c4 = (idx & 15) * 4;
    *(float4*)&As[row][c4] = ld4<AL>(&d[(by * 64 + row) * NN + r * 64 + c4]);
    *(float4*)&Bs[row][c4] = ld4<AL>(&d[(r * 64 + row) * NN + bx * 64 + c4]);
  }
  int tx = t & 15, ty = t >> 4;
  int i0 = ty * 4, j0 = tx * 4;
  int obase = (by * 64) * NN + bx * 64;
  float c[4][4];
#pragma unroll
  for (int ii = 0; ii < 4; ++ii) {
    float4 q = ld4<AL>(&d[obase + (i0 + ii) * NN + j0]);
    c[ii][0] = q.x; c[ii][1] = q.y; c[ii][2] = q.z; c[ii][3] = q.w;
  }
  __syncthreads();
  minplus16(As, Bs, c, i0, j0);

  bool closer = (bx == r + 1) && (by == r + 1) && (r + 1 < NT);
  if (closer) {
    __syncthreads();
#pragma unroll
    for (int ii = 0; ii < 4; ++ii)
      *(float4*)&As[i0 + ii][j0] = make_float4(c[ii][0], c[ii][1], c[ii][2], c[ii][3]);
    __syncthreads();
    close_seq(As, c, i0, j0, ty, tx);
  }
#pragma unroll
  for (int ii = 0; ii < 4; ++ii)
    st4<AL>(&d[obase + (i0 + ii) * NN + j0],
            make_float4(c[ii][0], c[ii][1], c[ii][2], c[ii][3]));
}

// ---------------------------------------------------------------------------
// anchors[rank] = i for rank < A (stable argsort(-nw) positions).
// ---------------------------------------------------------------------------
__global__ __launch_bounds__(256) void anchors_kernel(
    const float* __restrict__ nw, int* __restrict__ anchors) {
  __shared__ __align__(16) float s[NN];
  int t = threadIdx.x;
#pragma unroll
  for (int l = 0; l < NN / 256; ++l) s[l * 256 + t] = nw[l * 256 + t];
  __syncthreads();
  int i = blockIdx.x * 64 + (t >> 2);
  int q = t & 3;
  float wi = s[i];
  int rank = 0;
  int jb = q * (NN / 4);
  for (int j = jb; j < jb + NN / 4; j += 4) {
    float4 v = *(const float4*)&s[j];
    rank += (int)(v.x > wi) + ((int)(v.x == wi) & (int)(j + 0 < i));
    rank += (int)(v.y > wi) + ((int)(v.y == wi) & (int)(j + 1 < i));
    rank += (int)(v.z > wi) + ((int)(v.z == wi) & (int)(j + 2 < i));
    rank += (int)(v.w > wi) + ((int)(v.w == wi) & (int)(j + 3 < i));
  }
  rank += __shfl_xor(rank, 1);
  rank += __shfl_xor(rank, 2);
  if (q == 0 && rank < AA) anchors[rank] = i;
}

// ---------------------------------------------------------------------------
// Gather consensus_vectors (inf -> 100), accumulate global sum for the scalar.
// ---------------------------------------------------------------------------
__global__ __launch_bounds__(256) void cv_kernel(
    const float* __restrict__ dist, const int* __restrict__ anchors,
    float* __restrict__ cv_out, float* __restrict__ sum_acc) {
  int idx = blockIdx.x * 256 + threadIdx.x;   // 800*256 == 204800 exactly
  int i = idx / 100, a = idx - i * 100;
  float dv = dist[i * NN + anchors[a]];
  if (isinf(dv)) dv = 100.0f;
  cv_out[idx] = dv;
  float v = dv;
#pragma unroll
  for (int off = 32; off > 0; off >>= 1) v += __shfl_down(v, off);
  __shared__ float sv[4];
  int lane = threadIdx.x & 63, w = threadIdx.x >> 6;
  if (lane == 0) sv[w] = v;
  __syncthreads();
  if (threadIdx.x == 0) atomicAdd(sum_acc, sv[0] + sv[1] + sv[2] + sv[3]);
}

// ---------------------------------------------------------------------------
// consensus_graph: weighted = wm*cv on the fly; per-row xx in-block; K=100
// f32 dot + RBF epilogue.
// ---------------------------------------------------------------------------
__global__ __launch_bounds__(256) void graph_kernel(
    const float* __restrict__ wm, const float* __restrict__ cv,
    const float* __restrict__ sigma, float* __restrict__ graph) {
  __shared__ __align__(16) float As[64][108];
  __shared__ __align__(16) float Bs[64][108];
  __shared__ float xs[64], ys[64];
  int bx = blockIdx.x, by = blockIdx.y;
  int t = threadIdx.x;
#pragma unroll
  for (int l = 0; l < 7; ++l) {
    int idx = l * 256 + t;
    if (idx < 1600) {                 // 64 rows * 25 float4
      int row = idx / 25, c4 = (idx - row * 25) * 4;
      float4 wa = *(const float4*)&wm[(by * 64 + row) * AA + c4];
      float4 ca = *(const float4*)&cv[(by * 64 + row) * AA + c4];
      *(float4*)&As[row][c4] =
          make_float4(wa.x * ca.x, wa.y * ca.y, wa.z * ca.z, wa.w * ca.w);
      float4 wb = *(const float4*)&wm[(bx * 64 + row) * AA + c4];
      float4 cb = *(const float4*)&cv[(bx * 64 + row) * AA + c4];
      *(float4*)&Bs[row][c4] =
          make_float4(wb.x * cb.x, wb.y * cb.y, wb.z * cb.z, wb.w * cb.w);
    }
  }
  __syncthreads();
  if (t < 64) {
    float s = 0.0f;
    for (int k4 = 0; k4 < 25; ++k4) {
      float4 q = *(const float4*)&As[t][k4 * 4];
      s += q.x * q.x + q.y * q.y + q.z * q.z + q.w * q.w;
    }
    xs[t] = s;
  } else if (t < 128) {
    int r = t - 64;
    float s = 0.0f;
    for (int k4 = 0; k4 < 25; ++k4) {
      float4 q = *(const float4*)&Bs[r][k4 * 4];
      s += q.x * q.x + q.y * q.y + q.z * q.z + q.w * q.w;
    }
    ys[r] = s;
  }
  __syncthreads();
  int tx = t & 15, ty = t >> 4;
  float acc[4][4] = {{0.0f}};
#pragma unroll 5
  for (int k4 = 0; k4 < 25; ++k4) {
    int k = k4 * 4;
    float4 a_[4], b_[4];
#pragma unroll
    for (int ii = 0; ii < 4; ++ii) a_[ii] = *(const float4*)&As[ty + 16 * ii][k];
#pragma unroll
    for (int jj = 0; jj < 4; ++jj) b_[jj] = *(const float4*)&Bs[tx + 16 * jj][k];
#pragma unroll
    for (int ii = 0; ii < 4; ++ii)
#pragma unroll
      for (int jj = 0; jj < 4; ++jj)
        acc[ii][jj] += a_[ii].x * b_[jj].x + a_[ii].y * b_[jj].y +
                       a_[ii].z * b_[jj].z + a_[ii].w * b_[jj].w;
  }
  float s = *sigma;
  float inv2s2 = 0.5f / (s * s);
#pragma unroll
  for (int ii = 0; ii < 4; ++ii) {
    int gi = by * 64 + ty + 16 * ii;
    float xi = xs[ty + 16 * ii];
#pragma unroll
    for (int jj = 0; jj < 4; ++jj) {
      int gj = bx * 64 + tx + 16 * jj;
      float sq = fmaxf(xi + ys[tx + 16 * jj] - 2.0f * acc[ii][jj], 0.0f);
      graph[gi * NN + gj] = __expf(-(sq * sq) * inv2s2);
    }
  }
}

__global__ void finalize_kernel(const float* __restrict__ sum_acc,
                                float* __restrict__ out) {
  if (threadIdx.x == 0)
    *out = (*sum_acc - 204800.0f) / 204800.0f;  // (sum - N*100) / (N*A)
}

// ---------------------------------------------------------------------------
template<bool AL>
static void run_fw_fallback(const float* mg, const float* nw, float* dist,
                            hipStream_t stream) {
  build_w_kernel<AL><<<dim3(NT, NT), 256, 0, stream>>>(mg, nw, dist);
  for (int r = 0; r < NT; ++r) {
    fw_p2<AL><<<dim3(NT, 2), 256, 0, stream>>>(dist, r);
    fw_p3<AL><<<dim3(NT, NT), 256, 0, stream>>>(dist, r);
  }
}

// Host-side, capture-safe cooperative-launch feasibility check (pure queries).
static bool coop_ok() {
  static int ok = -1;
  if (ok < 0) {
    int dev = 0;
    (void)hipGetDevice(&dev);
    int coopAttr = 0;
    (void)hipDeviceGetAttribute(&coopAttr, hipDeviceAttributeCooperativeLaunch, dev);
    int cus = 0;
    (void)hipDeviceGetAttribute(&cus, hipDeviceAttributeMultiprocessorCount, dev);
    int nb = 0;
    hipError_t e = hipOccupancyMaxActiveBlocksPerMultiprocessor(&nb, fw_persist, 256, 0);
    ok = (e == hipSuccess && coopAttr && nb > 0 && (long)nb * cus >= NT * NT) ? 1 : 0;
  }
  return ok == 1;
}

extern "C" void kernel_launch(void* const* d_in, const int* in_sizes, int n_in,
                              void* d_out, int out_size, void* d_ws, size_t ws_size,
                              hipStream_t stream) {
  (void)in_sizes; (void)n_in; (void)out_size;
  const float* mg    = (const float*)d_in[0];
  const float* nw    = (const float*)d_in[1];
  const float* wm    = (const float*)d_in[2];
  const float* sigma = (const float*)d_in[3];
  float* out        = (float*)d_out;
  float* cv_out     = out;            // 2048*100
  float* scalar_out = out + 204800;   // 1
  float* graph_out  = out + 204801;   // 2048*2048

  float* W = (float*)d_ws;
  float* sum_acc = W;                 // W[0]
  int* anchors   = (int*)(W + 4);     // 100 ints (W[4..103])
  // ints W[128..1215]: custom grid barrier (root/gen/leaves) — see gridbar().
  const bool bigws = ws_size >= (size_t)(2048 + (size_t)NN * NN) * sizeof(float);
  float* dist = bigws ? (W + 2048) : graph_out;
  const bool al = ((((uintptr_t)dist) & 15) == 0);

  // Zero sum_acc + barrier state (stream-ordered; graph-safe; 8 KB).
  hipMemsetAsync(W, 0, 2048 * sizeof(float), stream);

  bool launched = false;
  if (bigws && al && coop_ok()) {
    int* Wi = (int*)W;
    void* args[] = {(void*)&mg, (void*)&nw, (void*)&dist, (void*)&Wi};
    hipError_t ce = hipLaunchCooperativeKernel(fw_persist, dim3(NT, NT),
                                               dim3(256, 1, 1), args, 0, stream);
    launched = (ce == hipSuccess);
  }
  if (!launched) {
    if (al) run_fw_fallback<true>(mg, nw, dist, stream);
    else    run_fw_fallback<false>(mg, nw, dist, stream);
  }

  anchors_kernel<<<NN / 64, 256, 0, stream>>>(nw, anchors);
  cv_kernel<<<800, 256, 0, stream>>>(dist, anchors, cv_out, sum_acc);
  graph_kernel<<<dim3(NT, NT), 256, 0, stream>>>(wm, cv_out, sigma, graph_out);
  finalize_kernel<<<1, 64, 0, stream>>>(sum_acc, scalar_out);
}

// Round 5
// 1083.628 us; speedup vs baseline: 1.0145x; 1.0145x over previous
//
#include <hip/hip_runtime.h>
#include <stdint.h>

// Problem constants (reference: N=2048, A=100)
#define NN 2048
#define AA 100
#define NT 32   // 64-wide tiles per side (2048/64)

// Flag arrays (int offsets within workspace Wi). All one-shot (0 -> 1),
// zeroed by a stream-ordered memset each launch.
#define F_DIAG 256    // [33]
#define F_ROW  512    // [32*32]
#define F_COL  1536   // [32*32]

// ---------------------------------------------------------------------------
// Alignment-templated global float4 access (fallback path may be 4B-aligned).
// ---------------------------------------------------------------------------
template<bool AL> __device__ __forceinline__ float4 ld4(const float* __restrict__ p) {
  if (AL) return *(const float4*)p;
  return make_float4(p[0], p[1], p[2], p[3]);
}
template<bool AL> __device__ __forceinline__ void st4(float* __restrict__ p, float4 v) {
  if (AL) { *(float4*)p = v; }
  else { p[0] = v.x; p[1] = v.y; p[2] = v.z; p[3] = v.w; }
}

// ---------------------------------------------------------------------------
// k=64 min-plus inner loop: c[4][4] = min(c, A(i0-rows) (x) B(j0-cols)).
// All LDS reads are b128; fminf chains fold to v_min3_f32 pairs.
// ---------------------------------------------------------------------------
__device__ __forceinline__ void minplus16(const float (*A)[68], const float (*B)[68],
                                          float c[4][4], int i0, int j0) {
#pragma unroll 4
  for (int k4 = 0; k4 < 16; ++k4) {
    const int k = k4 * 4;
    float4 a0 = *(const float4*)&A[i0 + 0][k];
    float4 a1 = *(const float4*)&A[i0 + 1][k];
    float4 a2 = *(const float4*)&A[i0 + 2][k];
    float4 a3 = *(const float4*)&A[i0 + 3][k];
    float4 b0 = *(const float4*)&B[k + 0][j0];
    float4 b1 = *(const float4*)&B[k + 1][j0];
    float4 b2 = *(const float4*)&B[k + 2][j0];
    float4 b3 = *(const float4*)&B[k + 3][j0];
#define MP1(ii, jj, f)                                                           \
    c[ii][jj] = fminf(fminf(fminf(fminf(c[ii][jj], a##ii.x + b0.f),              \
                                  a##ii.y + b1.f),                               \
                            a##ii.z + b2.f),                                     \
                      a##ii.w + b3.f)
#define MP_ROW(ii) MP1(ii, 0, x); MP1(ii, 1, y); MP1(ii, 2, z); MP1(ii, 3, w)
    MP_ROW(0); MP_ROW(1); MP_ROW(2); MP_ROW(3);
#undef MP_ROW
#undef MP1
  }
}

// ---------------------------------------------------------------------------
// Sequential-k Floyd-Warshall closure of the 64x64 tile in S.
// Thread owns c[4][4] == S's (i0,j0) block; S current on entry (caller
// barriers). Row k / col k are fixed points of step k, so only row/col k+1
// owners write back per step; one barrier per k. kq unrolled => static c[].
// ---------------------------------------------------------------------------
__device__ __forceinline__ void close_seq(float (*S)[68], float c[4][4],
                                          int i0, int j0, int ty, int tx) {
  for (int kb = 0; kb < 16; ++kb) {
#pragma unroll
    for (int kq = 0; kq < 4; ++kq) {
      const int k = kb * 4 + kq;
      float4 br = *(const float4*)&S[k][j0];
      float a0 = S[i0 + 0][k];
      float a1 = S[i0 + 1][k];
      float a2 = S[i0 + 2][k];
      float a3 = S[i0 + 3][k];
      c[0][0] = fminf(c[0][0], a0 + br.x); c[0][1] = fminf(c[0][1], a0 + br.y);
      c[0][2] = fminf(c[0][2], a0 + br.z); c[0][3] = fminf(c[0][3], a0 + br.w);
      c[1][0] = fminf(c[1][0], a1 + br.x); c[1][1] = fminf(c[1][1], a1 + br.y);
      c[1][2] = fminf(c[1][2], a1 + br.z); c[1][3] = fminf(c[1][3], a1 + br.w);
      c[2][0] = fminf(c[2][0], a2 + br.x); c[2][1] = fminf(c[2][1], a2 + br.y);
      c[2][2] = fminf(c[2][2], a2 + br.z); c[2][3] = fminf(c[2][3], a2 + br.w);
      c[3][0] = fminf(c[3][0], a3 + br.x); c[3][1] = fminf(c[3][1], a3 + br.y);
      c[3][2] = fminf(c[3][2], a3 + br.z); c[3][3] = fminf(c[3][3], a3 + br.w);
      const int kn = k + 1;
      const int ii = (kq + 1) & 3;   // == kn - i0 (resp. kn - j0) when owner
      if (kn < 64) {
        if ((kn >> 2) == ty)
          *(float4*)&S[kn][j0] = make_float4(c[ii][0], c[ii][1], c[ii][2], c[ii][3]);
        if ((kn >> 2) == tx) {
          S[i0 + 0][kn] = c[0][ii];
          S[i0 + 1][kn] = c[1][ii];
          S[i0 + 2][kn] = c[2][ii];
          S[i0 + 3][kn] = c[3][ii];
        }
      }
      __syncthreads();
    }
  }
}

// ---------------------------------------------------------------------------
// Dataflow primitives. Flags are one-shot; publishers: plain stores ->
// __syncthreads (drains vmcnt of all waves) -> thread0: __threadfence
// (L2 writeback to the coherence point) + agent release store. Readers:
// thread0 spins (agent relaxed loads bypass the per-XCD L2), then
// __threadfence (invalidate) BEFORE __syncthreads releases the loads.
// LAZY is the s_sleep immediate (must be a compile-time constant).
// ---------------------------------------------------------------------------
template<int LAZY>
__device__ __forceinline__ void waitflag(int* f) {
  int it = 0;
  while (__hip_atomic_load(f, __ATOMIC_RELAXED, __HIP_MEMORY_SCOPE_AGENT) == 0) {
    if (++it > 24) __builtin_amdgcn_s_sleep(LAZY);
  }
}
__device__ __forceinline__ void setflag(int* f) {
  __hip_atomic_store(f, 1, __ATOMIC_RELEASE, __HIP_MEMORY_SCOPE_AGENT);
}

// stage a contiguous 64x64 (stride-64) global tile into padded LDS
__device__ __forceinline__ void stage64(const float* __restrict__ g,
                                        float (*S)[68], int t) {
#pragma unroll
  for (int l = 0; l < 4; ++l) {
    int idx = l * 256 + t;
    int row = idx >> 4, c4 = (idx & 15) * 4;
    *(float4*)&S[row][c4] = *(const float4*)&g[row * 64 + c4];
  }
}
// publish c[4][4] into a contiguous 64x64 (stride-64) global tile
__device__ __forceinline__ void pub64(float* __restrict__ g,
                                      const float c[4][4], int i0, int j0) {
#pragma unroll
  for (int ii = 0; ii < 4; ++ii)
    *(float4*)&g[(i0 + ii) * 64 + j0] =
        make_float4(c[ii][0], c[ii][1], c[ii][2], c[ii][3]);
}

// ===========================================================================
// DATAFLOW PERSISTENT FW KERNEL — no grid barriers at all.
// Block (by,bx) owns tile (by,bx) in registers for all 32 rounds.
// Per-(round,tile) publish buffers (written exactly once each):
//   DIAG[r]     closed diagonal tile of round r
//   ROW[r][bx]  tile (r,bx) after its round-r diag multiply  (B-operands)
//   COL[by][r]  tile (by,r) after its round-r diag multiply  (A-operands)
// Round r, block roles:
//   diag (r,r):      idle (it closed itself at end of round r-1)
//   row-cross (r,bx): wait DIAGF[r];  C=min(C,diag(x)C);  pub ROW + flag
//   col-cross (by,r): wait DIAGF[r];  C=min(C,C(x)diag);  pub COL + flag
//   off-cross:        wait ROWF[r][bx] & COLF[by][r]; C=min(C,A(x)B)
//   closer (r+1,r+1): off-cross work, then close_seq, pub DIAG[r+1] + flag
// Only the diag chain is latency-critical; the other ~960 blocks lag freely.
// Cooperative launch retained ONLY for co-residency (spin safety).
// ===========================================================================
__global__ __launch_bounds__(256, 4) void fw_persist(
    const float* __restrict__ mg, const float* __restrict__ nw,
    float* __restrict__ dist, int* __restrict__ Wi,
    float* __restrict__ diagb, float* __restrict__ rowb,
    float* __restrict__ colb) {
  __shared__ __align__(16) float As[64][68];
  __shared__ __align__(16) float Bs[64][68];
  const int bx = blockIdx.x, by = blockIdx.y;
  const int t = threadIdx.x;
  const int tx = t & 15, ty = t >> 4;
  const int i0 = ty * 4, j0 = tx * 4;
  int* DIAGF = Wi + F_DIAG;
  int* ROWF  = Wi + F_ROW;
  int* COLF  = Wi + F_COL;

  // ---- init: build w tile (by,bx) directly into registers (fused build_w) --
  // Bs[c][r] = mg[bx*64+r][by*64+c]  (transposed stage of mg tile (bx,by))
#pragma unroll
  for (int l = 0; l < 4; ++l) {
    int idx = l * 256 + t;
    int r = idx >> 4, c4 = (idx & 15) * 4;
    float4 g = *(const float4*)&mg[(bx * 64 + r) * NN + by * 64 + c4];
    Bs[c4 + 0][r] = g.x; Bs[c4 + 1][r] = g.y;
    Bs[c4 + 2][r] = g.z; Bs[c4 + 3][r] = g.w;
  }
  __syncthreads();
  float c[4][4];
  {
    float4 nwj = *(const float4*)&nw[bx * 64 + j0];
#pragma unroll
    for (int ii = 0; ii < 4; ++ii) {
      int rl = i0 + ii;
      int i = by * 64 + rl;
      float nwi = nw[i];
      float4 m = *(const float4*)&mg[i * NN + bx * 64 + j0];
      float4 bt = *(const float4*)&Bs[rl][j0];   // = mg[j][i]
      float av[4] = {m.x * nwi, m.y * nwi, m.z * nwi, m.w * nwi};
      float bv[4] = {bt.x * nwj.x, bt.y * nwj.y, bt.z * nwj.z, bt.w * nwj.w};
#pragma unroll
      for (int q = 0; q < 4; ++q) {
        float wa = av[q] > 0.0f ? av[q] : __builtin_huge_valf();
        float wb = bv[q] > 0.0f ? bv[q] : __builtin_huge_valf();
        float v = fminf(wa, wb);
        if (i == bx * 64 + j0 + q) v = 0.0f;
        c[ii][q] = v;
      }
    }
  }
  // block (0,0): close its tile and publish DIAG[0]
  if (bx == 0 && by == 0) {
    __syncthreads();
#pragma unroll
    for (int ii = 0; ii < 4; ++ii)
      *(float4*)&As[i0 + ii][j0] = make_float4(c[ii][0], c[ii][1], c[ii][2], c[ii][3]);
    __syncthreads();
    close_seq(As, c, i0, j0, ty, tx);
    pub64(diagb, c, i0, j0);
    __syncthreads();   // drain all waves' publish stores
    if (t == 0) { __threadfence(); setflag(DIAGF + 0); }
  }

  for (int r = 0; r < NT; ++r) {
    if (by == r && bx == r) continue;        // diag: closed last round, idle
    if (by == r || bx == r) {
      // ---- cross tile: wait closed diag, multiply, publish panel ----------
      const bool isRow = (by == r);          // row: A=diag,B=own; col: A=own,B=diag
      __syncthreads();                       // prior-round LDS reads complete
      float (*Ow)[68] = isRow ? Bs : As;
#pragma unroll
      for (int ii = 0; ii < 4; ++ii)
        *(float4*)&Ow[i0 + ii][j0] =
            make_float4(c[ii][0], c[ii][1], c[ii][2], c[ii][3]);
      if (t == 0) { waitflag<1>(DIAGF + r); __threadfence(); }
      __syncthreads();                       // flag seen + caches invalidated
      stage64(diagb + r * 4096, isRow ? As : Bs, t);
      __syncthreads();
      minplus16(As, Bs, c, i0, j0);
      float* ob = isRow ? rowb + (r * NT + bx) * 4096
                        : colb + (by * NT + r) * 4096;
      pub64(ob, c, i0, j0);
      __syncthreads();                       // drain publish stores
      if (t == 0) {
        __threadfence();
        setflag(isRow ? ROWF + r * NT + bx : COLF + by * NT + r);
      }
    } else {
      // ---- off-cross: wait the two panels; closer also closes next diag ---
      const bool closer = (bx == r + 1) && (by == r + 1) && (r + 1 < NT);
      if (closer) __builtin_amdgcn_s_setprio(1);
      if (t == 0) {
        if (closer) {
          waitflag<1>(ROWF + r * NT + bx);
          waitflag<1>(COLF + by * NT + r);
        } else {
          waitflag<8>(ROWF + r * NT + bx);
          waitflag<8>(COLF + by * NT + r);
        }
        __threadfence();
      }
      __syncthreads();                       // also separates prior LDS reads
      stage64(colb + (by * NT + r) * 4096, As, t);   // A-op = tile (by,r)
      stage64(rowb + (r * NT + bx) * 4096, Bs, t);   // B-op = tile (r,bx)
      __syncthreads();
      minplus16(As, Bs, c, i0, j0);
      if (closer) {
        __syncthreads();                     // all As/Bs reads of minplus done
#pragma unroll
        for (int ii = 0; ii < 4; ++ii)
          *(float4*)&As[i0 + ii][j0] =
              make_float4(c[ii][0], c[ii][1], c[ii][2], c[ii][3]);
        __syncthreads();
        close_seq(As, c, i0, j0, ty, tx);
        pub64(diagb + (r + 1) * 4096, c, i0, j0);
        __syncthreads();
        if (t == 0) { __threadfence(); setflag(DIAGF + r + 1); }
        __builtin_amdgcn_s_setprio(0);
      }
    }
  }

  // ---- final publish of all tiles for cv_kernel ----
  float* ob = &dist[(by * 64) * NN + bx * 64];
#pragma unroll
  for (int ii = 0; ii < 4; ++ii)
    *(float4*)&ob[(i0 + ii) * NN + j0] =
        make_float4(c[ii][0], c[ii][1], c[ii][2], c[ii][3]);
}

// ===========================================================================
// FALLBACK multi-dispatch path (r1 kernels, unchanged)
// ===========================================================================
template<bool AL>
__global__ __launch_bounds__(256) void build_w_kernel(
    const float* __restrict__ mg, const float* __restrict__ nw,
    float* __restrict__ w) {
  __shared__ float Tt[64][65];
  __shared__ __align__(16) float As[64][68];
  int bi = blockIdx.y, bj = blockIdx.x;
  int t = threadIdx.x;
  const bool diag0 = (bi == 0) && (bj == 0);
#pragma unroll
  for (int l = 0; l < 4; ++l) {
    int idx = l * 256 + t;
    int r = idx >> 4, c4 = (idx & 15) * 4;
    float4 g = *(const float4*)&mg[(bj * 64 + r) * NN + bi * 64 + c4];
    Tt[c4 + 0][r] = g.x; Tt[c4 + 1][r] = g.y;
    Tt[c4 + 2][r] = g.z; Tt[c4 + 3][r] = g.w;
  }
  __syncthreads();
#pragma unroll
  for (int l = 0; l < 4; ++l) {
    int idx = l * 256 + t;
    int r = idx >> 4, c4 = (idx & 15) * 4;
    int i = bi * 64 + r, j = bj * 64 + c4;
    float4 m = *(const float4*)&mg[i * NN + j];
    float4 nwj = *(const float4*)&nw[j];
    float nwi = nw[i];
    float av[4] = {m.x * nwi, m.y * nwi, m.z * nwi, m.w * nwi};
    float bv[4] = {Tt[r][c4 + 0] * nwj.x, Tt[r][c4 + 1] * nwj.y,
                   Tt[r][c4 + 2] * nwj.z, Tt[r][c4 + 3] * nwj.w};
    float vv[4];
#pragma unroll
    for (int q = 0; q < 4; ++q) {
      float wa = av[q] > 0.0f ? av[q] : __builtin_huge_valf();
      float wb = bv[q] > 0.0f ? bv[q] : __builtin_huge_valf();
      float v = fminf(wa, wb);
      if (i == j + q) v = 0.0f;
      vv[q] = v;
    }
    float4 v4 = make_float4(vv[0], vv[1], vv[2], vv[3]);
    if (diag0) {
      *(float4*)&As[r][c4] = v4;
    } else {
      st4<AL>(&w[i * NN + j], v4);
    }
  }
  if (diag0) {
    __syncthreads();
    int tx = t & 15, ty = t >> 4;
    int i0 = ty * 4, j0 = tx * 4;
    float c[4][4];
#pragma unroll
    for (int ii = 0; ii < 4; ++ii) {
      float4 q = *(const float4*)&As[i0 + ii][j0];
      c[ii][0] = q.x; c[ii][1] = q.y; c[ii][2] = q.z; c[ii][3] = q.w;
    }
    close_seq(As, c, i0, j0, ty, tx);
#pragma unroll
    for (int ii = 0; ii < 4; ++ii)
      st4<AL>(&w[(i0 + ii) * NN + j0],
              make_float4(c[ii][0], c[ii][1], c[ii][2], c[ii][3]));
  }
}

template<bool AL>
__global__ __launch_bounds__(256) void fw_p2(float* __restrict__ d, int r) {
  __shared__ __align__(16) float As[64][68];
  __shared__ __align__(16) float Bs[64][68];
  int tile = blockIdx.x, side = blockIdx.y;
  if (tile == r) return;
  int t = threadIdx.x;
  int dbase = (r * 64) * NN + r * 64;
  int obase = (side == 0) ? (r * 64) * NN + tile * 64
                          : (tile * 64) * NN + r * 64;
  float (*Da)[68] = (side == 0) ? As : Bs;
  float (*Ow)[68] = (side == 0) ? Bs : As;
#pragma unroll
  for (int l = 0; l < 4; ++l) {
    int idx = l * 256 + t;
    int row = idx >> 4, c4 = (idx & 15) * 4;
    *(float4*)&Da[row][c4] = ld4<AL>(&d[dbase + row * NN + c4]);
    *(float4*)&Ow[row][c4] = ld4<AL>(&d[obase + row * NN + c4]);
  }
  int tx = t & 15, ty = t >> 4;
  int i0 = ty * 4, j0 = tx * 4;
  __syncthreads();
  float c[4][4];
#pragma unroll
  for (int ii = 0; ii < 4; ++ii) {
    float4 q = *(const float4*)&Ow[i0 + ii][j0];
    c[ii][0] = q.x; c[ii][1] = q.y; c[ii][2] = q.z; c[ii][3] = q.w;
  }
  minplus16(As, Bs, c, i0, j0);
#pragma unroll
  for (int ii = 0; ii < 4; ++ii)
    st4<AL>(&d[obase + (i0 + ii) * NN + j0],
            make_float4(c[ii][0], c[ii][1], c[ii][2], c[ii][3]));
}

template<bool AL>
__global__ __launch_bounds__(256) void fw_p3(float* __restrict__ d, int r) {
  __shared__ __align__(16) float As[64][68];
  __shared__ __align__(16) float Bs[64][68];
  int bx = blockIdx.x, by = blockIdx.y;
  if (bx == r || by == r) return;
  int t = threadIdx.x;
#pragma unroll
  for (int l = 0; l < 4; ++l) {
    int idx = l * 256 + t;
    int row = idx >> 4, c4 = (idx & 15) * 4;
    *(float4*)&As[row][c4] = ld4<AL>(&d[(by * 64 + row) * NN + r * 64 + c4]);
    *(float4*)&Bs[row][c4] = ld4<AL>(&d[(r * 64 + row) * NN + bx * 64 + c4]);
  }
  int tx = t & 15, ty = t >> 4;
  int i0 = ty * 4, j0 = tx * 4;
  int obase = (by * 64) * NN + bx * 64;
  float c[4][4];
#pragma unroll
  for (int ii = 0; ii < 4; ++ii) {
    float4 q = ld4<AL>(&d[obase + (i0 + ii) * NN + j0]);
    c[ii][0] = q.x; c[ii][1] = q.y; c[ii][2] = q.z; c[ii][3] = q.w;
  }
  __syncthreads();
  minplus16(As, Bs, c, i0, j0);

  bool closer = (bx == r + 1) && (by == r + 1) && (r + 1 < NT);
  if (closer) {
    __syncthreads();
#pragma unroll
    for (int ii = 0; ii < 4; ++ii)
      *(float4*)&As[i0 + ii][j0] = make_float4(c[ii][0], c[ii][1], c[ii][2], c[ii][3]);
    __syncthreads();
    close_seq(As, c, i0, j0, ty, tx);
  }
#pragma unroll
  for (int ii = 0; ii < 4; ++ii)
    st4<AL>(&d[obase + (i0 + ii) * NN + j0],
            make_float4(c[ii][0], c[ii][1], c[ii][2], c[ii][3]));
}

// ---------------------------------------------------------------------------
// anchors[rank] = i for rank < A (stable argsort(-nw) positions).
// ---------------------------------------------------------------------------
__global__ __launch_bounds__(256) void anchors_kernel(
    const float* __restrict__ nw, int* __restrict__ anchors) {
  __shared__ __align__(16) float s[NN];
  int t = threadIdx.x;
#pragma unroll
  for (int l = 0; l < NN / 256; ++l) s[l * 256 + t] = nw[l * 256 + t];
  __syncthreads();
  int i = blockIdx.x * 64 + (t >> 2);
  int q = t & 3;
  float wi = s[i];
  int rank = 0;
  int jb = q * (NN / 4);
  for (int j = jb; j < jb + NN / 4; j += 4) {
    float4 v = *(const float4*)&s[j];
    rank += (int)(v.x > wi) + ((int)(v.x == wi) & (int)(j + 0 < i));
    rank += (int)(v.y > wi) + ((int)(v.y == wi) & (int)(j + 1 < i));
    rank += (int)(v.z > wi) + ((int)(v.z == wi) & (int)(j + 2 < i));
    rank += (int)(v.w > wi) + ((int)(v.w == wi) & (int)(j + 3 < i));
  }
  rank += __shfl_xor(rank, 1);
  rank += __shfl_xor(rank, 2);
  if (q == 0 && rank < AA) anchors[rank] = i;
}

// ---------------------------------------------------------------------------
// Gather consensus_vectors (inf -> 100), accumulate global sum for the scalar.
// ---------------------------------------------------------------------------
__global__ __launch_bounds__(256) void cv_kernel(
    const float* __restrict__ dist, const int* __restrict__ anchors,
    float* __restrict__ cv_out, float* __restrict__ sum_acc) {
  int idx = blockIdx.x * 256 + threadIdx.x;   // 800*256 == 204800 exactly
  int i = idx / 100, a = idx - i * 100;
  float dv = dist[i * NN + anchors[a]];
  if (isinf(dv)) dv = 100.0f;
  cv_out[idx] = dv;
  float v = dv;
#pragma unroll
  for (int off = 32; off > 0; off >>= 1) v += __shfl_down(v, off);
  __shared__ float sv[4];
  int lane = threadIdx.x & 63, w = threadIdx.x >> 6;
  if (lane == 0) sv[w] = v;
  __syncthreads();
  if (threadIdx.x == 0) atomicAdd(sum_acc, sv[0] + sv[1] + sv[2] + sv[3]);
}

// ---------------------------------------------------------------------------
// consensus_graph: weighted = wm*cv on the fly; per-row xx in-block; K=100
// f32 dot + RBF epilogue.
// ---------------------------------------------------------------------------
__global__ __launch_bounds__(256) void graph_kernel(
    const float* __restrict__ wm, const float* __restrict__ cv,
    const float* __restrict__ sigma, float* __restrict__ graph) {
  __shared__ __align__(16) float As[64][108];
  __shared__ __align__(16) float Bs[64][108];
  __shared__ float xs[64], ys[64];
  int bx = blockIdx.x, by = blockIdx.y;
  int t = threadIdx.x;
#pragma unroll
  for (int l = 0; l < 7; ++l) {
    int idx = l * 256 + t;
    if (idx < 1600) {                 // 64 rows * 25 float4
      int row = idx / 25, c4 = (idx - row * 25) * 4;
      float4 wa = *(const float4*)&wm[(by * 64 + row) * AA + c4];
      float4 ca = *(const float4*)&cv[(by * 64 + row) * AA + c4];
      *(float4*)&As[row][c4] =
          make_float4(wa.x * ca.x, wa.y * ca.y, wa.z * ca.z, wa.w * ca.w);
      float4 wb = *(const float4*)&wm[(bx * 64 + row) * AA + c4];
      float4 cb = *(const float4*)&cv[(bx * 64 + row) * AA + c4];
      *(float4*)&Bs[row][c4] =
          make_float4(wb.x * cb.x, wb.y * cb.y, wb.z * cb.z, wb.w * cb.w);
    }
  }
  __syncthreads();
  if (t < 64) {
    float s = 0.0f;
    for (int k4 = 0; k4 < 25; ++k4) {
      float4 q = *(const float4*)&As[t][k4 * 4];
      s += q.x * q.x + q.y * q.y + q.z * q.z + q.w * q.w;
    }
    xs[t] = s;
  } else if (t < 128) {
    int r = t - 64;
    float s = 0.0f;
    for (int k4 = 0; k4 < 25; ++k4) {
      float4 q = *(const float4*)&Bs[r][k4 * 4];
      s += q.x * q.x + q.y * q.y + q.z * q.z + q.w * q.w;
    }
    ys[r] = s;
  }
  __syncthreads();
  int tx = t & 15, ty = t >> 4;
  float acc[4][4] = {{0.0f}};
#pragma unroll 5
  for (int k4 = 0; k4 < 25; ++k4) {
    int k = k4 * 4;
    float4 a_[4], b_[4];
#pragma unroll
    for (int ii = 0; ii < 4; ++ii) a_[ii] = *(const float4*)&As[ty + 16 * ii][k];
#pragma unroll
    for (int jj = 0; jj < 4; ++jj) b_[jj] = *(const float4*)&Bs[tx + 16 * jj][k];
#pragma unroll
    for (int ii = 0; ii < 4; ++ii)
#pragma unroll
      for (int jj = 0; jj < 4; ++jj)
        acc[ii][jj] += a_[ii].x * b_[jj].x + a_[ii].y * b_[jj].y +
                       a_[ii].z * b_[jj].z + a_[ii].w * b_[jj].w;
  }
  float s = *sigma;
  float inv2s2 = 0.5f / (s * s);
#pragma unroll
  for (int ii = 0; ii < 4; ++ii) {
    int gi = by * 64 + ty + 16 * ii;
    float xi = xs[ty + 16 * ii];
#pragma unroll
    for (int jj = 0; jj < 4; ++jj) {
      int gj = bx * 64 + tx + 16 * jj;
      float sq = fmaxf(xi + ys[tx + 16 * jj] - 2.0f * acc[ii][jj], 0.0f);
      graph[gi * NN + gj] = __expf(-(sq * sq) * inv2s2);
    }
  }
}

__global__ void finalize_kernel(const float* __restrict__ sum_acc,
                                float* __restrict__ out) {
  if (threadIdx.x == 0)
    *out = (*sum_acc - 204800.0f) / 204800.0f;  // (sum - N*100) / (N*A)
}

// ---------------------------------------------------------------------------
template<bool AL>
static void run_fw_fallback(const float* mg, const float* nw, float* dist,
                            hipStream_t stream) {
  build_w_kernel<AL><<<dim3(NT, NT), 256, 0, stream>>>(mg, nw, dist);
  for (int r = 0; r < NT; ++r) {
    fw_p2<AL><<<dim3(NT, 2), 256, 0, stream>>>(dist, r);
    fw_p3<AL><<<dim3(NT, NT), 256, 0, stream>>>(dist, r);
  }
}

// Host-side, capture-safe cooperative-launch feasibility check (pure queries).
static bool coop_ok() {
  static int ok = -1;
  if (ok < 0) {
    int dev = 0;
    (void)hipGetDevice(&dev);
    int coopAttr = 0;
    (void)hipDeviceGetAttribute(&coopAttr, hipDeviceAttributeCooperativeLaunch, dev);
    int cus = 0;
    (void)hipDeviceGetAttribute(&cus, hipDeviceAttributeMultiprocessorCount, dev);
    int nb = 0;
    hipError_t e = hipOccupancyMaxActiveBlocksPerMultiprocessor(&nb, fw_persist, 256, 0);
    ok = (e == hipSuccess && coopAttr && nb > 0 && (long)nb * cus >= NT * NT) ? 1 : 0;
  }
  return ok == 1;
}

extern "C" void kernel_launch(void* const* d_in, const int* in_sizes, int n_in,
                              void* d_out, int out_size, void* d_ws, size_t ws_size,
                              hipStream_t stream) {
  (void)in_sizes; (void)n_in; (void)out_size;
  const float* mg    = (const float*)d_in[0];
  const float* nw    = (const float*)d_in[1];
  const float* wm    = (const float*)d_in[2];
  const float* sigma = (const float*)d_in[3];
  float* out        = (float*)d_out;
  float* cv_out     = out;            // 2048*100
  float* scalar_out = out + 204800;   // 1
  float* graph_out  = out + 204801;   // 2048*2048

  float* W = (float*)d_ws;
  float* sum_acc = W;                 // W[0]
  int* anchors   = (int*)(W + 4);     // 100 ints (W[4..103])
  // Wi[F_DIAG..]: dataflow flags (one-shot, re-zeroed per launch).
  // Float layout (persistent path):
  //   dist  @ W+16384                (NN*NN)
  //   DIAG  @ dist+NN*NN             (NT tiles  * 4096)
  //   ROW   @ DIAG+NT*4096           (NT*NT tiles * 4096)
  //   COL   @ ROW +NT*NT*4096        (NT*NT tiles * 4096)
  const size_t needP = (size_t)(16384 + (size_t)NN * NN + NT * 4096 +
                                2 * (size_t)NT * NT * 4096) * sizeof(float);  // ~51 MB
  const bool bigP  = ws_size >= needP;
  const bool bigF  = ws_size >= (size_t)(2048 + (size_t)NN * NN) * sizeof(float);
  float* dist = bigP ? (W + 16384) : (bigF ? (W + 2048) : graph_out);
  const bool al = ((((uintptr_t)dist) & 15) == 0);

  // Zero sum_acc + flags (16 KB, stream-ordered; re-runs on graph replay).
  (void)hipMemsetAsync(W, 0, 16384, stream);

  bool launched = false;
  if (bigP && al && coop_ok()) {
    int* Wi = (int*)W;
    float* diagb = dist + (size_t)NN * NN;
    float* rowb  = diagb + NT * 4096;
    float* colb  = rowb + (size_t)NT * NT * 4096;
    void* args[] = {(void*)&mg, (void*)&nw, (void*)&dist, (void*)&Wi,
                    (void*)&diagb, (void*)&rowb, (void*)&colb};
    hipError_t ce = hipLaunchCooperativeKernel(fw_persist, dim3(NT, NT),
                                               dim3(256, 1, 1), args, 0, stream);
    launched = (ce == hipSuccess);
  }
  if (!launched) {
    if (al) run_fw_fallback<true>(mg, nw, dist, stream);
    else    run_fw_fallback<false>(mg, nw, dist, stream);
  }

  anchors_kernel<<<NN / 64, 256, 0, stream>>>(nw, anchors);
  cv_kernel<<<800, 256, 0, stream>>>(dist, anchors, cv_out, sum_acc);
  graph_kernel<<<dim3(NT, NT), 256, 0, stream>>>(wm, cv_out, sigma, graph_out);
  finalize_kernel<<<1, 64, 0, stream>>>(sum_acc, scalar_out);
}

// Round 6
// 1057.510 us; speedup vs baseline: 1.0395x; 1.0247x over previous
//
#include <hip/hip_runtime.h>
#include <stdint.h>

// Problem constants (reference: N=2048, A=100)
#define NN 2048
#define AA 100
#define NT 32   // 64-wide tiles per side (2048/64)

// Flag arrays (int offsets within workspace Wi). All one-shot (0 -> 1),
// zeroed by a stream-ordered memset each launch.
#define F_DIAG 256    // [33]
#define F_ROW  512    // [32*32]
#define F_COL  1536   // [32*32]

// ---------------------------------------------------------------------------
// Alignment-templated global float4 access (fallback path may be 4B-aligned).
// ---------------------------------------------------------------------------
template<bool AL> __device__ __forceinline__ float4 ld4(const float* __restrict__ p) {
  if (AL) return *(const float4*)p;
  return make_float4(p[0], p[1], p[2], p[3]);
}
template<bool AL> __device__ __forceinline__ void st4(float* __restrict__ p, float4 v) {
  if (AL) { *(float4*)p = v; }
  else { p[0] = v.x; p[1] = v.y; p[2] = v.z; p[3] = v.w; }
}

// ---------------------------------------------------------------------------
// k=64 min-plus inner loop: c[4][4] = min(c, A(i0-rows) (x) B(j0-cols)).
// All LDS reads are b128; fminf chains fold to v_min3_f32 pairs.
// ---------------------------------------------------------------------------
__device__ __forceinline__ void minplus16(const float (*A)[68], const float (*B)[68],
                                          float c[4][4], int i0, int j0) {
#pragma unroll 4
  for (int k4 = 0; k4 < 16; ++k4) {
    const int k = k4 * 4;
    float4 a0 = *(const float4*)&A[i0 + 0][k];
    float4 a1 = *(const float4*)&A[i0 + 1][k];
    float4 a2 = *(const float4*)&A[i0 + 2][k];
    float4 a3 = *(const float4*)&A[i0 + 3][k];
    float4 b0 = *(const float4*)&B[k + 0][j0];
    float4 b1 = *(const float4*)&B[k + 1][j0];
    float4 b2 = *(const float4*)&B[k + 2][j0];
    float4 b3 = *(const float4*)&B[k + 3][j0];
#define MP1(ii, jj, f)                                                           \
    c[ii][jj] = fminf(fminf(fminf(fminf(c[ii][jj], a##ii.x + b0.f),              \
                                  a##ii.y + b1.f),                               \
                            a##ii.z + b2.f),                                     \
                      a##ii.w + b3.f)
#define MP_ROW(ii) MP1(ii, 0, x); MP1(ii, 1, y); MP1(ii, 2, z); MP1(ii, 3, w)
    MP_ROW(0); MP_ROW(1); MP_ROW(2); MP_ROW(3);
#undef MP_ROW
#undef MP1
  }
}

// ---------------------------------------------------------------------------
// Sequential-k Floyd-Warshall closure of the 64x64 tile in S.
// Thread owns c[4][4] == S's (i0,j0) block; S current on entry (caller
// barriers). Row k / col k are fixed points of step k, so only row/col k+1
// owners write back per step; one barrier per k. kq unrolled => static c[].
// ---------------------------------------------------------------------------
__device__ __forceinline__ void close_seq(float (*S)[68], float c[4][4],
                                          int i0, int j0, int ty, int tx) {
  for (int kb = 0; kb < 16; ++kb) {
#pragma unroll
    for (int kq = 0; kq < 4; ++kq) {
      const int k = kb * 4 + kq;
      float4 br = *(const float4*)&S[k][j0];
      float a0 = S[i0 + 0][k];
      float a1 = S[i0 + 1][k];
      float a2 = S[i0 + 2][k];
      float a3 = S[i0 + 3][k];
      c[0][0] = fminf(c[0][0], a0 + br.x); c[0][1] = fminf(c[0][1], a0 + br.y);
      c[0][2] = fminf(c[0][2], a0 + br.z); c[0][3] = fminf(c[0][3], a0 + br.w);
      c[1][0] = fminf(c[1][0], a1 + br.x); c[1][1] = fminf(c[1][1], a1 + br.y);
      c[1][2] = fminf(c[1][2], a1 + br.z); c[1][3] = fminf(c[1][3], a1 + br.w);
      c[2][0] = fminf(c[2][0], a2 + br.x); c[2][1] = fminf(c[2][1], a2 + br.y);
      c[2][2] = fminf(c[2][2], a2 + br.z); c[2][3] = fminf(c[2][3], a2 + br.w);
      c[3][0] = fminf(c[3][0], a3 + br.x); c[3][1] = fminf(c[3][1], a3 + br.y);
      c[3][2] = fminf(c[3][2], a3 + br.z); c[3][3] = fminf(c[3][3], a3 + br.w);
      const int kn = k + 1;
      const int ii = (kq + 1) & 3;   // == kn - i0 (resp. kn - j0) when owner
      if (kn < 64) {
        if ((kn >> 2) == ty)
          *(float4*)&S[kn][j0] = make_float4(c[ii][0], c[ii][1], c[ii][2], c[ii][3]);
        if ((kn >> 2) == tx) {
          S[i0 + 0][kn] = c[0][ii];
          S[i0 + 1][kn] = c[1][ii];
          S[i0 + 2][kn] = c[2][ii];
          S[i0 + 3][kn] = c[3][ii];
        }
      }
      __syncthreads();
    }
  }
}

// ---------------------------------------------------------------------------
// Dataflow primitives — LLC-coherent publish, NO cache-maintenance fences.
//   Publisher: per-dword sc1 write-through stores (relaxed agent atomics;
//     leave L2 clean, land at the coherence point) -> __syncthreads (each
//     wave's vmcnt drains to 0 before s_barrier => stores complete) ->
//     thread0 RELAXED agent flag store (RELEASE would emit buffer_wbl2).
//   Reader: thread0 polls relaxed agent load -> __syncthreads -> plain cached
//     float4 loads. Safe: panel lines are touched only after their one-shot
//     publish (L2 invalidated at kernel start; no pre-flag reads), so no
//     stale L2 copy can exist, and cacheable reads restore L2 panel sharing.
// ---------------------------------------------------------------------------
template<int LAZY>
__device__ __forceinline__ void waitflag(int* f) {
  int it = 0;
  while (__hip_atomic_load(f, __ATOMIC_RELAXED, __HIP_MEMORY_SCOPE_AGENT) == 0) {
    if (++it > 24) __builtin_amdgcn_s_sleep(LAZY);
  }
}
__device__ __forceinline__ void setflag(int* f) {
  __hip_atomic_store(f, 1, __ATOMIC_RELAXED, __HIP_MEMORY_SCOPE_AGENT);
}

// stage a contiguous 64x64 (stride-64) global tile into padded LDS (cached)
__device__ __forceinline__ void stage64(const float* __restrict__ g,
                                        float (*S)[68], int t) {
#pragma unroll
  for (int l = 0; l < 4; ++l) {
    int idx = l * 256 + t;
    int row = idx >> 4, c4 = (idx & 15) * 4;
    *(float4*)&S[row][c4] = *(const float4*)&g[row * 64 + c4];
  }
}
// publish c[4][4] into a contiguous 64x64 global tile, sc1 write-through
__device__ __forceinline__ void pub64_wt(float* __restrict__ g,
                                         const float c[4][4], int i0, int j0) {
#pragma unroll
  for (int ii = 0; ii < 4; ++ii)
#pragma unroll
    for (int jj = 0; jj < 4; ++jj)
      __hip_atomic_store(&g[(i0 + ii) * 64 + j0 + jj], c[ii][jj],
                         __ATOMIC_RELAXED, __HIP_MEMORY_SCOPE_AGENT);
}

// ===========================================================================
// DATAFLOW PERSISTENT FW KERNEL — no grid barriers, no cache-wide fences.
// Block (by,bx) owns tile (by,bx) in registers for all 32 rounds.
// Per-(round,tile) one-shot publish buffers:
//   DIAG[r], ROW[r][bx], COL[by][r]  (each written exactly once, via sc1)
// Round r roles: diag idle; row/col-cross wait DIAGF[r], multiply, publish;
// off-cross wait ROWF/COLF, multiply; closer (r+1,r+1) additionally closes
// its tile (close_seq) and publishes DIAG[r+1]. Only the diag chain is
// latency-critical. Cooperative launch retained ONLY for co-residency.
// ===========================================================================
__global__ __launch_bounds__(256, 4) void fw_persist(
    const float* __restrict__ mg, const float* __restrict__ nw,
    float* __restrict__ dist, int* __restrict__ Wi,
    float* __restrict__ diagb, float* __restrict__ rowb,
    float* __restrict__ colb) {
  __shared__ __align__(16) float As[64][68];
  __shared__ __align__(16) float Bs[64][68];
  const int bx = blockIdx.x, by = blockIdx.y;
  const int t = threadIdx.x;
  const int tx = t & 15, ty = t >> 4;
  const int i0 = ty * 4, j0 = tx * 4;
  int* DIAGF = Wi + F_DIAG;
  int* ROWF  = Wi + F_ROW;
  int* COLF  = Wi + F_COL;

  // ---- init: build w tile (by,bx) directly into registers (fused build_w) --
  // Bs[c][r] = mg[bx*64+r][by*64+c]  (transposed stage of mg tile (bx,by))
#pragma unroll
  for (int l = 0; l < 4; ++l) {
    int idx = l * 256 + t;
    int r = idx >> 4, c4 = (idx & 15) * 4;
    float4 g = *(const float4*)&mg[(bx * 64 + r) * NN + by * 64 + c4];
    Bs[c4 + 0][r] = g.x; Bs[c4 + 1][r] = g.y;
    Bs[c4 + 2][r] = g.z; Bs[c4 + 3][r] = g.w;
  }
  __syncthreads();
  float c[4][4];
  {
    float4 nwj = *(const float4*)&nw[bx * 64 + j0];
#pragma unroll
    for (int ii = 0; ii < 4; ++ii) {
      int rl = i0 + ii;
      int i = by * 64 + rl;
      float nwi = nw[i];
      float4 m = *(const float4*)&mg[i * NN + bx * 64 + j0];
      float4 bt = *(const float4*)&Bs[rl][j0];   // = mg[j][i]
      float av[4] = {m.x * nwi, m.y * nwi, m.z * nwi, m.w * nwi};
      float bv[4] = {bt.x * nwj.x, bt.y * nwj.y, bt.z * nwj.z, bt.w * nwj.w};
#pragma unroll
      for (int q = 0; q < 4; ++q) {
        float wa = av[q] > 0.0f ? av[q] : __builtin_huge_valf();
        float wb = bv[q] > 0.0f ? bv[q] : __builtin_huge_valf();
        float v = fminf(wa, wb);
        if (i == bx * 64 + j0 + q) v = 0.0f;
        c[ii][q] = v;
      }
    }
  }
  // block (0,0): close its tile and publish DIAG[0]
  if (bx == 0 && by == 0) {
    __syncthreads();
#pragma unroll
    for (int ii = 0; ii < 4; ++ii)
      *(float4*)&As[i0 + ii][j0] = make_float4(c[ii][0], c[ii][1], c[ii][2], c[ii][3]);
    __syncthreads();
    close_seq(As, c, i0, j0, ty, tx);
    pub64_wt(diagb, c, i0, j0);
    __syncthreads();   // all waves' sc1 stores complete (vmcnt drained)
    if (t == 0) setflag(DIAGF + 0);
  }

  for (int r = 0; r < NT; ++r) {
    if (by == r && bx == r) continue;        // diag: closed last round, idle
    if (by == r || bx == r) {
      // ---- cross tile: wait closed diag, multiply, publish panel ----------
      const bool isRow = (by == r);          // row: A=diag,B=own; col: A=own,B=diag
      __syncthreads();                       // prior-round LDS reads complete
      float (*Ow)[68] = isRow ? Bs : As;
#pragma unroll
      for (int ii = 0; ii < 4; ++ii)
        *(float4*)&Ow[i0 + ii][j0] =
            make_float4(c[ii][0], c[ii][1], c[ii][2], c[ii][3]);
      if (t == 0) waitflag<1>(DIAGF + r);
      __syncthreads();                       // flag seen by all
      stage64(diagb + r * 4096, isRow ? As : Bs, t);
      __syncthreads();
      minplus16(As, Bs, c, i0, j0);
      float* ob = isRow ? rowb + (r * NT + bx) * 4096
                        : colb + (by * NT + r) * 4096;
      pub64_wt(ob, c, i0, j0);
      __syncthreads();                       // sc1 stores complete
      if (t == 0) setflag(isRow ? ROWF + r * NT + bx : COLF + by * NT + r);
    } else {
      // ---- off-cross: wait the two panels; closer also closes next diag ---
      const bool closer = (bx == r + 1) && (by == r + 1) && (r + 1 < NT);
      if (closer) __builtin_amdgcn_s_setprio(1);
      if (t == 0) {
        if (closer) {
          waitflag<1>(ROWF + r * NT + bx);
          waitflag<1>(COLF + by * NT + r);
        } else {
          waitflag<8>(ROWF + r * NT + bx);
          waitflag<8>(COLF + by * NT + r);
        }
      }
      __syncthreads();                       // also separates prior LDS reads
      stage64(colb + (by * NT + r) * 4096, As, t);   // A-op = tile (by,r)
      stage64(rowb + (r * NT + bx) * 4096, Bs, t);   // B-op = tile (r,bx)
      __syncthreads();
      minplus16(As, Bs, c, i0, j0);
      if (closer) {
        __syncthreads();                     // all As/Bs reads of minplus done
#pragma unroll
        for (int ii = 0; ii < 4; ++ii)
          *(float4*)&As[i0 + ii][j0] =
              make_float4(c[ii][0], c[ii][1], c[ii][2], c[ii][3]);
        __syncthreads();
        close_seq(As, c, i0, j0, ty, tx);
        pub64_wt(diagb + (r + 1) * 4096, c, i0, j0);
        __syncthreads();
        if (t == 0) setflag(DIAGF + r + 1);
        __builtin_amdgcn_s_setprio(0);
      }
    }
  }

  // ---- final publish of all tiles for cv_kernel ----
  float* ob = &dist[(by * 64) * NN + bx * 64];
#pragma unroll
  for (int ii = 0; ii < 4; ++ii)
    *(float4*)&ob[(i0 + ii) * NN + j0] =
        make_float4(c[ii][0], c[ii][1], c[ii][2], c[ii][3]);
}

// ===========================================================================
// FALLBACK multi-dispatch path (r1 kernels, unchanged)
// ===========================================================================
template<bool AL>
__global__ __launch_bounds__(256) void build_w_kernel(
    const float* __restrict__ mg, const float* __restrict__ nw,
    float* __restrict__ w) {
  __shared__ float Tt[64][65];
  __shared__ __align__(16) float As[64][68];
  int bi = blockIdx.y, bj = blockIdx.x;
  int t = threadIdx.x;
  const bool diag0 = (bi == 0) && (bj == 0);
#pragma unroll
  for (int l = 0; l < 4; ++l) {
    int idx = l * 256 + t;
    int r = idx >> 4, c4 = (idx & 15) * 4;
    float4 g = *(const float4*)&mg[(bj * 64 + r) * NN + bi * 64 + c4];
    Tt[c4 + 0][r] = g.x; Tt[c4 + 1][r] = g.y;
    Tt[c4 + 2][r] = g.z; Tt[c4 + 3][r] = g.w;
  }
  __syncthreads();
#pragma unroll
  for (int l = 0; l < 4; ++l) {
    int idx = l * 256 + t;
    int r = idx >> 4, c4 = (idx & 15) * 4;
    int i = bi * 64 + r, j = bj * 64 + c4;
    float4 m = *(const float4*)&mg[i * NN + j];
    float4 nwj = *(const float4*)&nw[j];
    float nwi = nw[i];
    float av[4] = {m.x * nwi, m.y * nwi, m.z * nwi, m.w * nwi};
    float bv[4] = {Tt[r][c4 + 0] * nwj.x, Tt[r][c4 + 1] * nwj.y,
                   Tt[r][c4 + 2] * nwj.z, Tt[r][c4 + 3] * nwj.w};
    float vv[4];
#pragma unroll
    for (int q = 0; q < 4; ++q) {
      float wa = av[q] > 0.0f ? av[q] : __builtin_huge_valf();
      float wb = bv[q] > 0.0f ? bv[q] : __builtin_huge_valf();
      float v = fminf(wa, wb);
      if (i == j + q) v = 0.0f;
      vv[q] = v;
    }
    float4 v4 = make_float4(vv[0], vv[1], vv[2], vv[3]);
    if (diag0) {
      *(float4*)&As[r][c4] = v4;
    } else {
      st4<AL>(&w[i * NN + j], v4);
    }
  }
  if (diag0) {
    __syncthreads();
    int tx = t & 15, ty = t >> 4;
    int i0 = ty * 4, j0 = tx * 4;
    float c[4][4];
#pragma unroll
    for (int ii = 0; ii < 4; ++ii) {
      float4 q = *(const float4*)&As[i0 + ii][j0];
      c[ii][0] = q.x; c[ii][1] = q.y; c[ii][2] = q.z; c[ii][3] = q.w;
    }
    close_seq(As, c, i0, j0, ty, tx);
#pragma unroll
    for (int ii = 0; ii < 4; ++ii)
      st4<AL>(&w[(i0 + ii) * NN + j0],
              make_float4(c[ii][0], c[ii][1], c[ii][2], c[ii][3]));
  }
}

template<bool AL>
__global__ __launch_bounds__(256) void fw_p2(float* __restrict__ d, int r) {
  __shared__ __align__(16) float As[64][68];
  __shared__ __align__(16) float Bs[64][68];
  int tile = blockIdx.x, side = blockIdx.y;
  if (tile == r) return;
  int t = threadIdx.x;
  int dbase = (r * 64) * NN + r * 64;
  int obase = (side == 0) ? (r * 64) * NN + tile * 64
                          : (tile * 64) * NN + r * 64;
  float (*Da)[68] = (side == 0) ? As : Bs;
  float (*Ow)[68] = (side == 0) ? Bs : As;
#pragma unroll
  for (int l = 0; l < 4; ++l) {
    int idx = l * 256 + t;
    int row = idx >> 4, c4 = (idx & 15) * 4;
    *(float4*)&Da[row][c4] = ld4<AL>(&d[dbase + row * NN + c4]);
    *(float4*)&Ow[row][c4] = ld4<AL>(&d[obase + row * NN + c4]);
  }
  int tx = t & 15, ty = t >> 4;
  int i0 = ty * 4, j0 = tx * 4;
  __syncthreads();
  float c[4][4];
#pragma unroll
  for (int ii = 0; ii < 4; ++ii) {
    float4 q = *(const float4*)&Ow[i0 + ii][j0];
    c[ii][0] = q.x; c[ii][1] = q.y; c[ii][2] = q.z; c[ii][3] = q.w;
  }
  minplus16(As, Bs, c, i0, j0);
#pragma unroll
  for (int ii = 0; ii < 4; ++ii)
    st4<AL>(&d[obase + (i0 + ii) * NN + j0],
            make_float4(c[ii][0], c[ii][1], c[ii][2], c[ii][3]));
}

template<bool AL>
__global__ __launch_bounds__(256) void fw_p3(float* __restrict__ d, int r) {
  __shared__ __align__(16) float As[64][68];
  __shared__ __align__(16) float Bs[64][68];
  int bx = blockIdx.x, by = blockIdx.y;
  if (bx == r || by == r) return;
  int t = threadIdx.x;
#pragma unroll
  for (int l = 0; l < 4; ++l) {
    int idx = l * 256 + t;
    int row = idx >> 4, c4 = (idx & 15) * 4;
    *(float4*)&As[row][c4] = ld4<AL>(&d[(by * 64 + row) * NN + r * 64 + c4]);
    *(float4*)&Bs[row][c4] = ld4<AL>(&d[(r * 64 + row) * NN + bx * 64 + c4]);
  }
  int tx = t & 15, ty = t >> 4;
  int i0 = ty * 4, j0 = tx * 4;
  int obase = (by * 64) * NN + bx * 64;
  float c[4][4];
#pragma unroll
  for (int ii = 0; ii < 4; ++ii) {
    float4 q = ld4<AL>(&d[obase + (i0 + ii) * NN + j0]);
    c[ii][0] = q.x; c[ii][1] = q.y; c[ii][2] = q.z; c[ii][3] = q.w;
  }
  __syncthreads();
  minplus16(As, Bs, c, i0, j0);

  bool closer = (bx == r + 1) && (by == r + 1) && (r + 1 < NT);
  if (closer) {
    __syncthreads();
#pragma unroll
    for (int ii = 0; ii < 4; ++ii)
      *(float4*)&As[i0 + ii][j0] = make_float4(c[ii][0], c[ii][1], c[ii][2], c[ii][3]);
    __syncthreads();
    close_seq(As, c, i0, j0, ty, tx);
  }
#pragma unroll
  for (int ii = 0; ii < 4; ++ii)
    st4<AL>(&d[obase + (i0 + ii) * NN + j0],
            make_float4(c[ii][0], c[ii][1], c[ii][2], c[ii][3]));
}

// ---------------------------------------------------------------------------
// anchors[rank] = i for rank < A (stable argsort(-nw) positions).
// ---------------------------------------------------------------------------
__global__ __launch_bounds__(256) void anchors_kernel(
    const float* __restrict__ nw, int* __restrict__ anchors) {
  __shared__ __align__(16) float s[NN];
  int t = threadIdx.x;
#pragma unroll
  for (int l = 0; l < NN / 256; ++l) s[l * 256 + t] = nw[l * 256 + t];
  __syncthreads();
  int i = blockIdx.x * 64 + (t >> 2);
  int q = t & 3;
  float wi = s[i];
  int rank = 0;
  int jb = q * (NN / 4);
  for (int j = jb; j < jb + NN / 4; j += 4) {
    float4 v = *(const float4*)&s[j];
    rank += (int)(v.x > wi) + ((int)(v.x == wi) & (int)(j + 0 < i));
    rank += (int)(v.y > wi) + ((int)(v.y == wi) & (int)(j + 1 < i));
    rank += (int)(v.z > wi) + ((int)(v.z == wi) & (int)(j + 2 < i));
    rank += (int)(v.w > wi) + ((int)(v.w == wi) & (int)(j + 3 < i));
  }
  rank += __shfl_xor(rank, 1);
  rank += __shfl_xor(rank, 2);
  if (q == 0 && rank < AA) anchors[rank] = i;
}

// ---------------------------------------------------------------------------
// Gather consensus_vectors (inf -> 100), accumulate global sum for the scalar.
// ---------------------------------------------------------------------------
__global__ __launch_bounds__(256) void cv_kernel(
    const float* __restrict__ dist, const int* __restrict__ anchors,
    float* __restrict__ cv_out, float* __restrict__ sum_acc) {
  int idx = blockIdx.x * 256 + threadIdx.x;   // 800*256 == 204800 exactly
  int i = idx / 100, a = idx - i * 100;
  float dv = dist[i * NN + anchors[a]];
  if (isinf(dv)) dv = 100.0f;
  cv_out[idx] = dv;
  float v = dv;
#pragma unroll
  for (int off = 32; off > 0; off >>= 1) v += __shfl_down(v, off);
  __shared__ float sv[4];
  int lane = threadIdx.x & 63, w = threadIdx.x >> 6;
  if (lane == 0) sv[w] = v;
  __syncthreads();
  if (threadIdx.x == 0) atomicAdd(sum_acc, sv[0] + sv[1] + sv[2] + sv[3]);
}

// ---------------------------------------------------------------------------
// consensus_graph: weighted = wm*cv on the fly; per-row xx in-block; K=100
// f32 dot + RBF epilogue.
// ---------------------------------------------------------------------------
__global__ __launch_bounds__(256) void graph_kernel(
    const float* __restrict__ wm, const float* __restrict__ cv,
    const float* __restrict__ sigma, float* __restrict__ graph) {
  __shared__ __align__(16) float As[64][108];
  __shared__ __align__(16) float Bs[64][108];
  __shared__ float xs[64], ys[64];
  int bx = blockIdx.x, by = blockIdx.y;
  int t = threadIdx.x;
#pragma unroll
  for (int l = 0; l < 7; ++l) {
    int idx = l * 256 + t;
    if (idx < 1600) {                 // 64 rows * 25 float4
      int row = idx / 25, c4 = (idx - row * 25) * 4;
      float4 wa = *(const float4*)&wm[(by * 64 + row) * AA + c4];
      float4 ca = *(const float4*)&cv[(by * 64 + row) * AA + c4];
      *(float4*)&As[row][c4] =
          make_float4(wa.x * ca.x, wa.y * ca.y, wa.z * ca.z, wa.w * ca.w);
      float4 wb = *(const float4*)&wm[(bx * 64 + row) * AA + c4];
      float4 cb = *(const float4*)&cv[(bx * 64 + row) * AA + c4];
      *(float4*)&Bs[row][c4] =
          make_float4(wb.x * cb.x, wb.y * cb.y, wb.z * cb.z, wb.w * cb.w);
    }
  }
  __syncthreads();
  if (t < 64) {
    float s = 0.0f;
    for (int k4 = 0; k4 < 25; ++k4) {
      float4 q = *(const float4*)&As[t][k4 * 4];
      s += q.x * q.x + q.y * q.y + q.z * q.z + q.w * q.w;
    }
    xs[t] = s;
  } else if (t < 128) {
    int r = t - 64;
    float s = 0.0f;
    for (int k4 = 0; k4 < 25; ++k4) {
      float4 q = *(const float4*)&Bs[r][k4 * 4];
      s += q.x * q.x + q.y * q.y + q.z * q.z + q.w * q.w;
    }
    ys[r] = s;
  }
  __syncthreads();
  int tx = t & 15, ty = t >> 4;
  float acc[4][4] = {{0.0f}};
#pragma unroll 5
  for (int k4 = 0; k4 < 25; ++k4) {
    int k = k4 * 4;
    float4 a_[4], b_[4];
#pragma unroll
    for (int ii = 0; ii < 4; ++ii) a_[ii] = *(const float4*)&As[ty + 16 * ii][k];
#pragma unroll
    for (int jj = 0; jj < 4; ++jj) b_[jj] = *(const float4*)&Bs[tx + 16 * jj][k];
#pragma unroll
    for (int ii = 0; ii < 4; ++ii)
#pragma unroll
      for (int jj = 0; jj < 4; ++jj)
        acc[ii][jj] += a_[ii].x * b_[jj].x + a_[ii].y * b_[jj].y +
                       a_[ii].z * b_[jj].z + a_[ii].w * b_[jj].w;
  }
  float s = *sigma;
  float inv2s2 = 0.5f / (s * s);
#pragma unroll
  for (int ii = 0; ii < 4; ++ii) {
    int gi = by * 64 + ty + 16 * ii;
    float xi = xs[ty + 16 * ii];
#pragma unroll
    for (int jj = 0; jj < 4; ++jj) {
      int gj = bx * 64 + tx + 16 * jj;
      float sq = fmaxf(xi + ys[tx + 16 * jj] - 2.0f * acc[ii][jj], 0.0f);
      graph[gi * NN + gj] = __expf(-(sq * sq) * inv2s2);
    }
  }
}

__global__ void finalize_kernel(const float* __restrict__ sum_acc,
                                float* __restrict__ out) {
  if (threadIdx.x == 0)
    *out = (*sum_acc - 204800.0f) / 204800.0f;  // (sum - N*100) / (N*A)
}

// ---------------------------------------------------------------------------
template<bool AL>
static void run_fw_fallback(const float* mg, const float* nw, float* dist,
                            hipStream_t stream) {
  build_w_kernel<AL><<<dim3(NT, NT), 256, 0, stream>>>(mg, nw, dist);
  for (int r = 0; r < NT; ++r) {
    fw_p2<AL><<<dim3(NT, 2), 256, 0, stream>>>(dist, r);
    fw_p3<AL><<<dim3(NT, NT), 256, 0, stream>>>(dist, r);
  }
}

// Host-side, capture-safe cooperative-launch feasibility check (pure queries).
static bool coop_ok() {
  static int ok = -1;
  if (ok < 0) {
    int dev = 0;
    (void)hipGetDevice(&dev);
    int coopAttr = 0;
    (void)hipDeviceGetAttribute(&coopAttr, hipDeviceAttributeCooperativeLaunch, dev);
    int cus = 0;
    (void)hipDeviceGetAttribute(&cus, hipDeviceAttributeMultiprocessorCount, dev);
    int nb = 0;
    hipError_t e = hipOccupancyMaxActiveBlocksPerMultiprocessor(&nb, fw_persist, 256, 0);
    ok = (e == hipSuccess && coopAttr && nb > 0 && (long)nb * cus >= NT * NT) ? 1 : 0;
  }
  return ok == 1;
}

extern "C" void kernel_launch(void* const* d_in, const int* in_sizes, int n_in,
                              void* d_out, int out_size, void* d_ws, size_t ws_size,
                              hipStream_t stream) {
  (void)in_sizes; (void)n_in; (void)out_size;
  const float* mg    = (const float*)d_in[0];
  const float* nw    = (const float*)d_in[1];
  const float* wm    = (const float*)d_in[2];
  const float* sigma = (const float*)d_in[3];
  float* out        = (float*)d_out;
  float* cv_out     = out;            // 2048*100
  float* scalar_out = out + 204800;   // 1
  float* graph_out  = out + 204801;   // 2048*2048

  float* W = (float*)d_ws;
  float* sum_acc = W;                 // W[0]
  int* anchors   = (int*)(W + 4);     // 100 ints (W[4..103])
  // Wi[F_DIAG..]: dataflow flags (one-shot, re-zeroed per launch).
  // Float layout (persistent path):
  //   dist  @ W+16384                (NN*NN)
  //   DIAG  @ dist+NN*NN             (NT tiles  * 4096)
  //   ROW   @ DIAG+NT*4096           (NT*NT tiles * 4096)
  //   COL   @ ROW +NT*NT*4096        (NT*NT tiles * 4096)
  const size_t needP = (size_t)(16384 + (size_t)NN * NN + NT * 4096 +
                                2 * (size_t)NT * NT * 4096) * sizeof(float);  // ~51 MB
  const bool bigP  = ws_size >= needP;
  const bool bigF  = ws_size >= (size_t)(2048 + (size_t)NN * NN) * sizeof(float);
  float* dist = bigP ? (W + 16384) : (bigF ? (W + 2048) : graph_out);
  const bool al = ((((uintptr_t)dist) & 15) == 0);

  // Zero sum_acc + flags (16 KB, stream-ordered; re-runs on graph replay).
  (void)hipMemsetAsync(W, 0, 16384, stream);

  bool launched = false;
  if (bigP && al && coop_ok()) {
    int* Wi = (int*)W;
    float* diagb = dist + (size_t)NN * NN;
    float* rowb  = diagb + NT * 4096;
    float* colb  = rowb + (size_t)NT * NT * 4096;
    void* args[] = {(void*)&mg, (void*)&nw, (void*)&dist, (void*)&Wi,
                    (void*)&diagb, (void*)&rowb, (void*)&colb};
    hipError_t ce = hipLaunchCooperativeKernel(fw_persist, dim3(NT, NT),
                                               dim3(256, 1, 1), args, 0, stream);
    launched = (ce == hipSuccess);
  }
  if (!launched) {
    if (al) run_fw_fallback<true>(mg, nw, dist, stream);
    else    run_fw_fallback<false>(mg, nw, dist, stream);
  }

  anchors_kernel<<<NN / 64, 256, 0, stream>>>(nw, anchors);
  cv_kernel<<<800, 256, 0, stream>>>(dist, anchors, cv_out, sum_acc);
  graph_kernel<<<dim3(NT, NT), 256, 0, stream>>>(wm, cv_out, sigma, graph_out);
  finalize_kernel<<<1, 64, 0, stream>>>(sum_acc, scalar_out);
}

// Round 7
// 921.746 us; speedup vs baseline: 1.1926x; 1.1473x over previous
//
#include <hip/hip_runtime.h>
#include <stdint.h>

// Problem constants (reference: N=2048, A=100)
#define NN 2048
#define AA 100
#define NT 32   // 64-wide tiles per side (2048/64)

// Flag arrays (int offsets within workspace Wi). All one-shot (0 -> 1),
// zeroed by a stream-ordered memset each launch.
#define F_DIAG 256    // [33]
#define F_ROW  512    // [32*32]
#define F_COL  1536   // [32*32]

typedef float floatx4 __attribute__((ext_vector_type(4)));

// ---------------------------------------------------------------------------
// Alignment-templated global float4 access (fallback path may be 4B-aligned).
// ---------------------------------------------------------------------------
template<bool AL> __device__ __forceinline__ float4 ld4(const float* __restrict__ p) {
  if (AL) return *(const float4*)p;
  return make_float4(p[0], p[1], p[2], p[3]);
}
template<bool AL> __device__ __forceinline__ void st4(float* __restrict__ p, float4 v) {
  if (AL) { *(float4*)p = v; }
  else { p[0] = v.x; p[1] = v.y; p[2] = v.z; p[3] = v.w; }
}

// ---------------------------------------------------------------------------
// k=64 min-plus inner loop: c[4][4] = min(c, A(i0-rows) (x) B(j0-cols)).
// All LDS reads are b128; fminf chains fold to v_min3_f32 pairs.
// ---------------------------------------------------------------------------
__device__ __forceinline__ void minplus16(const float (*A)[68], const float (*B)[68],
                                          float c[4][4], int i0, int j0) {
#pragma unroll 4
  for (int k4 = 0; k4 < 16; ++k4) {
    const int k = k4 * 4;
    float4 a0 = *(const float4*)&A[i0 + 0][k];
    float4 a1 = *(const float4*)&A[i0 + 1][k];
    float4 a2 = *(const float4*)&A[i0 + 2][k];
    float4 a3 = *(const float4*)&A[i0 + 3][k];
    float4 b0 = *(const float4*)&B[k + 0][j0];
    float4 b1 = *(const float4*)&B[k + 1][j0];
    float4 b2 = *(const float4*)&B[k + 2][j0];
    float4 b3 = *(const float4*)&B[k + 3][j0];
#define MP1(ii, jj, f)                                                           \
    c[ii][jj] = fminf(fminf(fminf(fminf(c[ii][jj], a##ii.x + b0.f),              \
                                  a##ii.y + b1.f),                               \
                            a##ii.z + b2.f),                                     \
                      a##ii.w + b3.f)
#define MP_ROW(ii) MP1(ii, 0, x); MP1(ii, 1, y); MP1(ii, 2, z); MP1(ii, 3, w)
    MP_ROW(0); MP_ROW(1); MP_ROW(2); MP_ROW(3);
#undef MP_ROW
#undef MP1
  }
}

// ---------------------------------------------------------------------------
// PAIR-STEPPED sequential-k FW closure of the 64x64 tile in S (32 barriers).
// Per pair (k,k+1), k even: locally form post-step-k row k+1 (brp) and col
// k+1 (e_i) from step-k operands, apply both steps to c, then owners write
// rows/cols k+2,k+3 (post-pair) and ONE barrier. Values only decrease and
// every value is a real path length, so the 4B-granular LDS overlap of the
// writeback with other threads' scalar operand reads is benign (reading the
// fresher value only adds admissible relaxations).
// ---------------------------------------------------------------------------
__device__ __forceinline__ void close_seq(float (*S)[68], float c[4][4],
                                          int i0, int j0, int ty, int tx) {
  for (int kb = 0; kb < 16; ++kb) {
#pragma unroll
    for (int h = 0; h < 2; ++h) {
      const int k = kb * 4 + h * 2;
      float4 br  = *(const float4*)&S[k][j0];
      float4 br2 = *(const float4*)&S[k + 1][j0];
      float dkk1 = S[k][k + 1];
      float dk1k = S[k + 1][k];
      float a0 = S[i0 + 0][k],     a1 = S[i0 + 1][k],
            a2 = S[i0 + 2][k],     a3 = S[i0 + 3][k];
      float e0 = S[i0 + 0][k + 1], e1 = S[i0 + 1][k + 1],
            e2 = S[i0 + 2][k + 1], e3 = S[i0 + 3][k + 1];
      float4 brp;
      brp.x = fminf(br2.x, dk1k + br.x);
      brp.y = fminf(br2.y, dk1k + br.y);
      brp.z = fminf(br2.z, dk1k + br.z);
      brp.w = fminf(br2.w, dk1k + br.w);
      e0 = fminf(e0, a0 + dkk1);
      e1 = fminf(e1, a1 + dkk1);
      e2 = fminf(e2, a2 + dkk1);
      e3 = fminf(e3, a3 + dkk1);
#define CS2(ii, aa, ee)                                                     \
      c[ii][0] = fminf(fminf(c[ii][0], aa + br.x), ee + brp.x);             \
      c[ii][1] = fminf(fminf(c[ii][1], aa + br.y), ee + brp.y);             \
      c[ii][2] = fminf(fminf(c[ii][2], aa + br.z), ee + brp.z);             \
      c[ii][3] = fminf(fminf(c[ii][3], aa + br.w), ee + brp.w)
      CS2(0, a0, e0); CS2(1, a1, e1); CS2(2, a2, e2); CS2(3, a3, e3);
#undef CS2
      const int kn = k + 2;                 // rows/cols kn, kn+1 share owner
      if (kn < 64) {
        const int ow = kn >> 2;
        const int ri = (h == 0) ? 2 : 0;    // kn & 3, compile-time per h
        if (ow == ty) {
          *(float4*)&S[kn][j0] =
              make_float4(c[ri][0], c[ri][1], c[ri][2], c[ri][3]);
          *(float4*)&S[kn + 1][j0] =
              make_float4(c[ri + 1][0], c[ri + 1][1], c[ri + 1][2], c[ri + 1][3]);
        }
        if (ow == tx) {
          S[i0 + 0][kn] = c[0][ri]; S[i0 + 0][kn + 1] = c[0][ri + 1];
          S[i0 + 1][kn] = c[1][ri]; S[i0 + 1][kn + 1] = c[1][ri + 1];
          S[i0 + 2][kn] = c[2][ri]; S[i0 + 2][kn + 1] = c[2][ri + 1];
          S[i0 + 3][kn] = c[3][ri]; S[i0 + 3][kn + 1] = c[3][ri + 1];
        }
      }
      __syncthreads();
    }
  }
}

// ---------------------------------------------------------------------------
// Dataflow primitives — LLC-coherent publish, NO cache-wide fences.
//   Publisher: float4 write-through stores (global_store_dwordx4 sc0 sc1 —
//     lane-contiguous full lines, land at the coherence point, leave L2
//     clean) -> s_waitcnt vmcnt(0) per thread -> __syncthreads -> thread0
//     RELAXED agent flag store (RELEASE would emit buffer_wbl2).
//   Reader: thread0 polls relaxed agent load -> __syncthreads -> plain cached
//     float4 loads. Safe: panel lines are touched only after their one-shot
//     publish (caches invalidated at dispatch start; no pre-flag reads), so
//     no stale copy can exist, and cacheable reads give L2 panel sharing.
// ---------------------------------------------------------------------------
template<int LAZY>
__device__ __forceinline__ void waitflag(int* f) {
  int it = 0;
  while (__hip_atomic_load(f, __ATOMIC_RELAXED, __HIP_MEMORY_SCOPE_AGENT) == 0) {
    if (++it > 24) __builtin_amdgcn_s_sleep(LAZY);
  }
}
__device__ __forceinline__ void setflag(int* f) {
  __hip_atomic_store(f, 1, __ATOMIC_RELAXED, __HIP_MEMORY_SCOPE_AGENT);
}

// stage a contiguous 64x64 (stride-64) global tile into padded LDS (cached)
__device__ __forceinline__ void stage64(const float* __restrict__ g,
                                        float (*S)[68], int t) {
#pragma unroll
  for (int l = 0; l < 4; ++l) {
    int idx = l * 256 + t;
    int row = idx >> 4, c4 = (idx & 15) * 4;
    *(float4*)&S[row][c4] = *(const float4*)&g[row * 64 + c4];
  }
}
// publish c[4][4] into a contiguous 64x64 global tile: write-through float4
__device__ __forceinline__ void pub64_wt(float* __restrict__ g,
                                         const float c[4][4], int i0, int j0) {
#pragma unroll
  for (int ii = 0; ii < 4; ++ii) {
    floatx4 v = {c[ii][0], c[ii][1], c[ii][2], c[ii][3]};
    float* p = &g[(i0 + ii) * 64 + j0];
    asm volatile("global_store_dwordx4 %0, %1, off sc0 sc1"
                 :: "v"(p), "v"(v) : "memory");
  }
  asm volatile("s_waitcnt vmcnt(0)" ::: "memory");   // this thread's stores done
}

// ===========================================================================
// DATAFLOW PERSISTENT FW KERNEL — no grid barriers, no cache-wide fences.
// Block (by,bx) owns tile (by,bx) in registers for all 32 rounds.
// One-shot publish buffers: DIAG[r], ROW[r][bx], COL[by][r].
// Round r roles: diag idle; row/col-cross wait DIAGF[r], multiply, publish;
// off-cross wait ROWF/COLF, multiply; closer (r+1,r+1) additionally closes
// (pair-stepped close_seq) and publishes DIAG[r+1]. Critical set per round =
// rows/cols r and r+1 (~25% of blocks): these get s_setprio(1) + tight spin.
// Cooperative launch retained ONLY for co-residency (spin safety).
// ===========================================================================
__global__ __launch_bounds__(256, 4) void fw_persist(
    const float* __restrict__ mg, const float* __restrict__ nw,
    float* __restrict__ dist, int* __restrict__ Wi,
    float* __restrict__ diagb, float* __restrict__ rowb,
    float* __restrict__ colb) {
  __shared__ __align__(16) float As[64][68];
  __shared__ __align__(16) float Bs[64][68];
  const int bx = blockIdx.x, by = blockIdx.y;
  const int t = threadIdx.x;
  const int tx = t & 15, ty = t >> 4;
  const int i0 = ty * 4, j0 = tx * 4;
  int* DIAGF = Wi + F_DIAG;
  int* ROWF  = Wi + F_ROW;
  int* COLF  = Wi + F_COL;

  // ---- init: build w tile (by,bx) directly into registers (fused build_w) --
  // Bs[c][r] = mg[bx*64+r][by*64+c]  (transposed stage of mg tile (bx,by))
#pragma unroll
  for (int l = 0; l < 4; ++l) {
    int idx = l * 256 + t;
    int r = idx >> 4, c4 = (idx & 15) * 4;
    float4 g = *(const float4*)&mg[(bx * 64 + r) * NN + by * 64 + c4];
    Bs[c4 + 0][r] = g.x; Bs[c4 + 1][r] = g.y;
    Bs[c4 + 2][r] = g.z; Bs[c4 + 3][r] = g.w;
  }
  __syncthreads();
  float c[4][4];
  {
    float4 nwj = *(const float4*)&nw[bx * 64 + j0];
#pragma unroll
    for (int ii = 0; ii < 4; ++ii) {
      int rl = i0 + ii;
      int i = by * 64 + rl;
      float nwi = nw[i];
      float4 m = *(const float4*)&mg[i * NN + bx * 64 + j0];
      float4 bt = *(const float4*)&Bs[rl][j0];   // = mg[j][i]
      float av[4] = {m.x * nwi, m.y * nwi, m.z * nwi, m.w * nwi};
      float bv[4] = {bt.x * nwj.x, bt.y * nwj.y, bt.z * nwj.z, bt.w * nwj.w};
#pragma unroll
      for (int q = 0; q < 4; ++q) {
        float wa = av[q] > 0.0f ? av[q] : __builtin_huge_valf();
        float wb = bv[q] > 0.0f ? bv[q] : __builtin_huge_valf();
        float v = fminf(wa, wb);
        if (i == bx * 64 + j0 + q) v = 0.0f;
        c[ii][q] = v;
      }
    }
  }
  // block (0,0): close its tile and publish DIAG[0]
  if (bx == 0 && by == 0) {
    __syncthreads();
#pragma unroll
    for (int ii = 0; ii < 4; ++ii)
      *(float4*)&As[i0 + ii][j0] = make_float4(c[ii][0], c[ii][1], c[ii][2], c[ii][3]);
    __syncthreads();
    close_seq(As, c, i0, j0, ty, tx);
    pub64_wt(diagb, c, i0, j0);
    __syncthreads();   // all waves' stores drained (explicit vmcnt + barrier)
    if (t == 0) setflag(DIAGF + 0);
  }

  for (int r = 0; r < NT; ++r) {
    const bool crit = (by == r) || (bx == r) || (by == r + 1) || (bx == r + 1);
    if (crit) __builtin_amdgcn_s_setprio(1);
    else      __builtin_amdgcn_s_setprio(0);
    if (by == r && bx == r) continue;        // diag: closed last round, idle
    if (by == r || bx == r) {
      // ---- cross tile: wait closed diag, multiply, publish panel ----------
      const bool isRow = (by == r);          // row: A=diag,B=own; col: A=own,B=diag
      __syncthreads();                       // prior-round LDS reads complete
      float (*Ow)[68] = isRow ? Bs : As;
#pragma unroll
      for (int ii = 0; ii < 4; ++ii)
        *(float4*)&Ow[i0 + ii][j0] =
            make_float4(c[ii][0], c[ii][1], c[ii][2], c[ii][3]);
      if (t == 0) waitflag<1>(DIAGF + r);
      __syncthreads();                       // flag seen by all
      stage64(diagb + r * 4096, isRow ? As : Bs, t);
      __syncthreads();
      minplus16(As, Bs, c, i0, j0);
      float* ob = isRow ? rowb + (r * NT + bx) * 4096
                        : colb + (by * NT + r) * 4096;
      pub64_wt(ob, c, i0, j0);
      __syncthreads();                       // stores complete grid-visibly
      if (t == 0) setflag(isRow ? ROWF + r * NT + bx : COLF + by * NT + r);
    } else {
      // ---- off-cross: wait the two panels; closer also closes next diag ---
      const bool closer = (bx == r + 1) && (by == r + 1) && (r + 1 < NT);
      if (t == 0) {
        if (crit) {
          waitflag<1>(ROWF + r * NT + bx);
          waitflag<1>(COLF + by * NT + r);
        } else {
          waitflag<8>(ROWF + r * NT + bx);
          waitflag<8>(COLF + by * NT + r);
        }
      }
      __syncthreads();                       // also separates prior LDS reads
      stage64(colb + (by * NT + r) * 4096, As, t);   // A-op = tile (by,r)
      stage64(rowb + (r * NT + bx) * 4096, Bs, t);   // B-op = tile (r,bx)
      __syncthreads();
      minplus16(As, Bs, c, i0, j0);
      if (closer) {
        __syncthreads();                     // all As/Bs reads of minplus done
#pragma unroll
        for (int ii = 0; ii < 4; ++ii)
          *(float4*)&As[i0 + ii][j0] =
              make_float4(c[ii][0], c[ii][1], c[ii][2], c[ii][3]);
        __syncthreads();
        close_seq(As, c, i0, j0, ty, tx);
        pub64_wt(diagb + (r + 1) * 4096, c, i0, j0);
        __syncthreads();
        if (t == 0) setflag(DIAGF + r + 1);
      }
    }
  }
  __builtin_amdgcn_s_setprio(0);

  // ---- final publish of all tiles for cv_kernel ----
  float* ob = &dist[(by * 64) * NN + bx * 64];
#pragma unroll
  for (int ii = 0; ii < 4; ++ii)
    *(float4*)&ob[(i0 + ii) * NN + j0] =
        make_float4(c[ii][0], c[ii][1], c[ii][2], c[ii][3]);
}

// ===========================================================================
// FALLBACK multi-dispatch path (r1 kernels, unchanged)
// ===========================================================================
template<bool AL>
__global__ __launch_bounds__(256) void build_w_kernel(
    const float* __restrict__ mg, const float* __restrict__ nw,
    float* __restrict__ w) {
  __shared__ float Tt[64][65];
  __shared__ __align__(16) float As[64][68];
  int bi = blockIdx.y, bj = blockIdx.x;
  int t = threadIdx.x;
  const bool diag0 = (bi == 0) && (bj == 0);
#pragma unroll
  for (int l = 0; l < 4; ++l) {
    int idx = l * 256 + t;
    int r = idx >> 4, c4 = (idx & 15) * 4;
    float4 g = *(const float4*)&mg[(bj * 64 + r) * NN + bi * 64 + c4];
    Tt[c4 + 0][r] = g.x; Tt[c4 + 1][r] = g.y;
    Tt[c4 + 2][r] = g.z; Tt[c4 + 3][r] = g.w;
  }
  __syncthreads();
#pragma unroll
  for (int l = 0; l < 4; ++l) {
    int idx = l * 256 + t;
    int r = idx >> 4, c4 = (idx & 15) * 4;
    int i = bi * 64 + r, j = bj * 64 + c4;
    float4 m = *(const float4*)&mg[i * NN + j];
    float4 nwj = *(const float4*)&nw[j];
    float nwi = nw[i];
    float av[4] = {m.x * nwi, m.y * nwi, m.z * nwi, m.w * nwi};
    float bv[4] = {Tt[r][c4 + 0] * nwj.x, Tt[r][c4 + 1] * nwj.y,
                   Tt[r][c4 + 2] * nwj.z, Tt[r][c4 + 3] * nwj.w};
    float vv[4];
#pragma unroll
    for (int q = 0; q < 4; ++q) {
      float wa = av[q] > 0.0f ? av[q] : __builtin_huge_valf();
      float wb = bv[q] > 0.0f ? bv[q] : __builtin_huge_valf();
      float v = fminf(wa, wb);
      if (i == j + q) v = 0.0f;
      vv[q] = v;
    }
    float4 v4 = make_float4(vv[0], vv[1], vv[2], vv[3]);
    if (diag0) {
      *(float4*)&As[r][c4] = v4;
    } else {
      st4<AL>(&w[i * NN + j], v4);
    }
  }
  if (diag0) {
    __syncthreads();
    int tx = t & 15, ty = t >> 4;
    int i0 = ty * 4, j0 = tx * 4;
    float c[4][4];
#pragma unroll
    for (int ii = 0; ii < 4; ++ii) {
      float4 q = *(const float4*)&As[i0 + ii][j0];
      c[ii][0] = q.x; c[ii][1] = q.y; c[ii][2] = q.z; c[ii][3] = q.w;
    }
    close_seq(As, c, i0, j0, ty, tx);
#pragma unroll
    for (int ii = 0; ii < 4; ++ii)
      st4<AL>(&w[(i0 + ii) * NN + j0],
              make_float4(c[ii][0], c[ii][1], c[ii][2], c[ii][3]));
  }
}

template<bool AL>
__global__ __launch_bounds__(256) void fw_p2(float* __restrict__ d, int r) {
  __shared__ __align__(16) float As[64][68];
  __shared__ __align__(16) float Bs[64][68];
  int tile = blockIdx.x, side = blockIdx.y;
  if (tile == r) return;
  int t = threadIdx.x;
  int dbase = (r * 64) * NN + r * 64;
  int obase = (side == 0) ? (r * 64) * NN + tile * 64
                          : (tile * 64) * NN + r * 64;
  float (*Da)[68] = (side == 0) ? As : Bs;
  float (*Ow)[68] = (side == 0) ? Bs : As;
#pragma unroll
  for (int l = 0; l < 4; ++l) {
    int idx = l * 256 + t;
    int row = idx >> 4, c4 = (idx & 15) * 4;
    *(float4*)&Da[row][c4] = ld4<AL>(&d[dbase + row * NN + c4]);
    *(float4*)&Ow[row][c4] = ld4<AL>(&d[obase + row * NN + c4]);
  }
  int tx = t & 15, ty = t >> 4;
  int i0 = ty * 4, j0 = tx * 4;
  __syncthreads();
  float c[4][4];
#pragma unroll
  for (int ii = 0; ii < 4; ++ii) {
    float4 q = *(const float4*)&Ow[i0 + ii][j0];
    c[ii][0] = q.x; c[ii][1] = q.y; c[ii][2] = q.z; c[ii][3] = q.w;
  }
  minplus16(As, Bs, c, i0, j0);
#pragma unroll
  for (int ii = 0; ii < 4; ++ii)
    st4<AL>(&d[obase + (i0 + ii) * NN + j0],
            make_float4(c[ii][0], c[ii][1], c[ii][2], c[ii][3]));
}

template<bool AL>
__global__ __launch_bounds__(256) void fw_p3(float* __restrict__ d, int r) {
  __shared__ __align__(16) float As[64][68];
  __shared__ __align__(16) float Bs[64][68];
  int bx = blockIdx.x, by = blockIdx.y;
  if (bx == r || by == r) return;
  int t = threadIdx.x;
#pragma unroll
  for (int l = 0; l < 4; ++l) {
    int idx = l * 256 + t;
    int row = idx >> 4, c4 = (idx & 15) * 4;
    *(float4*)&As[row][c4] = ld4<AL>(&d[(by * 64 + row) * NN + r * 64 + c4]);
    *(float4*)&Bs[row][c4] = ld4<AL>(&d[(r * 64 + row) * NN + bx * 64 + c4]);
  }
  int tx = t & 15, ty = t >> 4;
  int i0 = ty * 4, j0 = tx * 4;
  int obase = (by * 64) * NN + bx * 64;
  float c[4][4];
#pragma unroll
  for (int ii = 0; ii < 4; ++ii) {
    float4 q = ld4<AL>(&d[obase + (i0 + ii) * NN + j0]);
    c[ii][0] = q.x; c[ii][1] = q.y; c[ii][2] = q.z; c[ii][3] = q.w;
  }
  __syncthreads();
  minplus16(As, Bs, c, i0, j0);

  bool closer = (bx == r + 1) && (by == r + 1) && (r + 1 < NT);
  if (closer) {
    __syncthreads();
#pragma unroll
    for (int ii = 0; ii < 4; ++ii)
      *(float4*)&As[i0 + ii][j0] = make_float4(c[ii][0], c[ii][1], c[ii][2], c[ii][3]);
    __syncthreads();
    close_seq(As, c, i0, j0, ty, tx);
  }
#pragma unroll
  for (int ii = 0; ii < 4; ++ii)
    st4<AL>(&d[obase + (i0 + ii) * NN + j0],
            make_float4(c[ii][0], c[ii][1], c[ii][2], c[ii][3]));
}

// ---------------------------------------------------------------------------
// anchors[rank] = i for rank < A (stable argsort(-nw) positions).
// ---------------------------------------------------------------------------
__global__ __launch_bounds__(256) void anchors_kernel(
    const float* __restrict__ nw, int* __restrict__ anchors) {
  __shared__ __align__(16) float s[NN];
  int t = threadIdx.x;
#pragma unroll
  for (int l = 0; l < NN / 256; ++l) s[l * 256 + t] = nw[l * 256 + t];
  __syncthreads();
  int i = blockIdx.x * 64 + (t >> 2);
  int q = t & 3;
  float wi = s[i];
  int rank = 0;
  int jb = q * (NN / 4);
  for (int j = jb; j < jb + NN / 4; j += 4) {
    float4 v = *(const float4*)&s[j];
    rank += (int)(v.x > wi) + ((int)(v.x == wi) & (int)(j + 0 < i));
    rank += (int)(v.y > wi) + ((int)(v.y == wi) & (int)(j + 1 < i));
    rank += (int)(v.z > wi) + ((int)(v.z == wi) & (int)(j + 2 < i));
    rank += (int)(v.w > wi) + ((int)(v.w == wi) & (int)(j + 3 < i));
  }
  rank += __shfl_xor(rank, 1);
  rank += __shfl_xor(rank, 2);
  if (q == 0 && rank < AA) anchors[rank] = i;
}

// ---------------------------------------------------------------------------
// Gather consensus_vectors (inf -> 100), accumulate global sum for the scalar.
// ---------------------------------------------------------------------------
__global__ __launch_bounds__(256) void cv_kernel(
    const float* __restrict__ dist, const int* __restrict__ anchors,
    float* __restrict__ cv_out, float* __restrict__ sum_acc) {
  int idx = blockIdx.x * 256 + threadIdx.x;   // 800*256 == 204800 exactly
  int i = idx / 100, a = idx - i * 100;
  float dv = dist[i * NN + anchors[a]];
  if (isinf(dv)) dv = 100.0f;
  cv_out[idx] = dv;
  float v = dv;
#pragma unroll
  for (int off = 32; off > 0; off >>= 1) v += __shfl_down(v, off);
  __shared__ float sv[4];
  int lane = threadIdx.x & 63, w = threadIdx.x >> 6;
  if (lane == 0) sv[w] = v;
  __syncthreads();
  if (threadIdx.x == 0) atomicAdd(sum_acc, sv[0] + sv[1] + sv[2] + sv[3]);
}

// ---------------------------------------------------------------------------
// consensus_graph: weighted = wm*cv on the fly; per-row xx in-block; K=100
// f32 dot + RBF epilogue.
// ---------------------------------------------------------------------------
__global__ __launch_bounds__(256) void graph_kernel(
    const float* __restrict__ wm, const float* __restrict__ cv,
    const float* __restrict__ sigma, float* __restrict__ graph) {
  __shared__ __align__(16) float As[64][108];
  __shared__ __align__(16) float Bs[64][108];
  __shared__ float xs[64], ys[64];
  int bx = blockIdx.x, by = blockIdx.y;
  int t = threadIdx.x;
#pragma unroll
  for (int l = 0; l < 7; ++l) {
    int idx = l * 256 + t;
    if (idx < 1600) {                 // 64 rows * 25 float4
      int row = idx / 25, c4 = (idx - row * 25) * 4;
      float4 wa = *(const float4*)&wm[(by * 64 + row) * AA + c4];
      float4 ca = *(const float4*)&cv[(by * 64 + row) * AA + c4];
      *(float4*)&As[row][c4] =
          make_float4(wa.x * ca.x, wa.y * ca.y, wa.z * ca.z, wa.w * ca.w);
      float4 wb = *(const float4*)&wm[(bx * 64 + row) * AA + c4];
      float4 cb = *(const float4*)&cv[(bx * 64 + row) * AA + c4];
      *(float4*)&Bs[row][c4] =
          make_float4(wb.x * cb.x, wb.y * cb.y, wb.z * cb.z, wb.w * cb.w);
    }
  }
  __syncthreads();
  if (t < 64) {
    float s = 0.0f;
    for (int k4 = 0; k4 < 25; ++k4) {
      float4 q = *(const float4*)&As[t][k4 * 4];
      s += q.x * q.x + q.y * q.y + q.z * q.z + q.w * q.w;
    }
    xs[t] = s;
  } else if (t < 128) {
    int r = t - 64;
    float s = 0.0f;
    for (int k4 = 0; k4 < 25; ++k4) {
      float4 q = *(const float4*)&Bs[r][k4 * 4];
      s += q.x * q.x + q.y * q.y + q.z * q.z + q.w * q.w;
    }
    ys[r] = s;
  }
  __syncthreads();
  int tx = t & 15, ty = t >> 4;
  float acc[4][4] = {{0.0f}};
#pragma unroll 5
  for (int k4 = 0; k4 < 25; ++k4) {
    int k = k4 * 4;
    float4 a_[4], b_[4];
#pragma unroll
    for (int ii = 0; ii < 4; ++ii) a_[ii] = *(const float4*)&As[ty + 16 * ii][k];
#pragma unroll
    for (int jj = 0; jj < 4; ++jj) b_[jj] = *(const float4*)&Bs[tx + 16 * jj][k];
#pragma unroll
    for (int ii = 0; ii < 4; ++ii)
#pragma unroll
      for (int jj = 0; jj < 4; ++jj)
        acc[ii][jj] += a_[ii].x * b_[jj].x + a_[ii].y * b_[jj].y +
                       a_[ii].z * b_[jj].z + a_[ii].w * b_[jj].w;
  }
  float s = *sigma;
  float inv2s2 = 0.5f / (s * s);
#pragma unroll
  for (int ii = 0; ii < 4; ++ii) {
    int gi = by * 64 + ty + 16 * ii;
    float xi = xs[ty + 16 * ii];
#pragma unroll
    for (int jj = 0; jj < 4; ++jj) {
      int gj = bx * 64 + tx + 16 * jj;
      float sq = fmaxf(xi + ys[tx + 16 * jj] - 2.0f * acc[ii][jj], 0.0f);
      graph[gi * NN + gj] = __expf(-(sq * sq) * inv2s2);
    }
  }
}

__global__ void finalize_kernel(const float* __restrict__ sum_acc,
                                float* __restrict__ out) {
  if (threadIdx.x == 0)
    *out = (*sum_acc - 204800.0f) / 204800.0f;  // (sum - N*100) / (N*A)
}

// ---------------------------------------------------------------------------
template<bool AL>
static void run_fw_fallback(const float* mg, const float* nw, float* dist,
                            hipStream_t stream) {
  build_w_kernel<AL><<<dim3(NT, NT), 256, 0, stream>>>(mg, nw, dist);
  for (int r = 0; r < NT; ++r) {
    fw_p2<AL><<<dim3(NT, 2), 256, 0, stream>>>(dist, r);
    fw_p3<AL><<<dim3(NT, NT), 256, 0, stream>>>(dist, r);
  }
}

// Host-side, capture-safe cooperative-launch feasibility check (pure queries).
static bool coop_ok() {
  static int ok = -1;
  if (ok < 0) {
    int dev = 0;
    (void)hipGetDevice(&dev);
    int coopAttr = 0;
    (void)hipDeviceGetAttribute(&coopAttr, hipDeviceAttributeCooperativeLaunch, dev);
    int cus = 0;
    (void)hipDeviceGetAttribute(&cus, hipDeviceAttributeMultiprocessorCount, dev);
    int nb = 0;
    hipError_t e = hipOccupancyMaxActiveBlocksPerMultiprocessor(&nb, fw_persist, 256, 0);
    ok = (e == hipSuccess && coopAttr && nb > 0 && (long)nb * cus >= NT * NT) ? 1 : 0;
  }
  return ok == 1;
}

extern "C" void kernel_launch(void* const* d_in, const int* in_sizes, int n_in,
                              void* d_out, int out_size, void* d_ws, size_t ws_size,
                              hipStream_t stream) {
  (void)in_sizes; (void)n_in; (void)out_size;
  const float* mg    = (const float*)d_in[0];
  const float* nw    = (const float*)d_in[1];
  const float* wm    = (const float*)d_in[2];
  const float* sigma = (const float*)d_in[3];
  float* out        = (float*)d_out;
  float* cv_out     = out;            // 2048*100
  float* scalar_out = out + 204800;   // 1
  float* graph_out  = out + 204801;   // 2048*2048

  float* W = (float*)d_ws;
  float* sum_acc = W;                 // W[0]
  int* anchors   = (int*)(W + 4);     // 100 ints (W[4..103])
  // Wi[F_DIAG..]: dataflow flags (one-shot, re-zeroed per launch).
  // Float layout (persistent path):
  //   dist  @ W+16384                (NN*NN)
  //   DIAG  @ dist+NN*NN             (NT tiles  * 4096)
  //   ROW   @ DIAG+NT*4096           (NT*NT tiles * 4096)
  //   COL   @ ROW +NT*NT*4096        (NT*NT tiles * 4096)
  const size_t needP = (size_t)(16384 + (size_t)NN * NN + NT * 4096 +
                                2 * (size_t)NT * NT * 4096) * sizeof(float);  // ~51 MB
  const bool bigP  = ws_size >= needP;
  const bool bigF  = ws_size >= (size_t)(2048 + (size_t)NN * NN) * sizeof(float);
  float* dist = bigP ? (W + 16384) : (bigF ? (W + 2048) : graph_out);
  const bool al = ((((uintptr_t)dist) & 15) == 0);

  // Zero sum_acc + flags (16 KB, stream-ordered; re-runs on graph replay).
  (void)hipMemsetAsync(W, 0, 16384, stream);

  bool launched = false;
  if (bigP && al && coop_ok()) {
    int* Wi = (int*)W;
    float* diagb = dist + (size_t)NN * NN;
    float* rowb  = diagb + NT * 4096;
    float* colb  = rowb + (size_t)NT * NT * 4096;
    void* args[] = {(void*)&mg, (void*)&nw, (void*)&dist, (void*)&Wi,
                    (void*)&diagb, (void*)&rowb, (void*)&colb};
    hipError_t ce = hipLaunchCooperativeKernel(fw_persist, dim3(NT, NT),
                                               dim3(256, 1, 1), args, 0, stream);
    launched = (ce == hipSuccess);
  }
  if (!launched) {
    if (al) run_fw_fallback<true>(mg, nw, dist, stream);
    else    run_fw_fallback<false>(mg, nw, dist, stream);
  }

  anchors_kernel<<<NN / 64, 256, 0, stream>>>(nw, anchors);
  cv_kernel<<<800, 256, 0, stream>>>(dist, anchors, cv_out, sum_acc);
  graph_kernel<<<dim3(NT, NT), 256, 0, stream>>>(wm, cv_out, sigma, graph_out);
  finalize_kernel<<<1, 64, 0, stream>>>(sum_acc, scalar_out);
}